// Round 6
// baseline (240.896 us; speedup 1.0000x reference)
//
#include <hip/hip_runtime.h>
#include <cstdint>

#define NUM_CLASSES 80
#define NPRED 8400
#define NBATCH 32
#define TOPK_N 1000
#define SORTN 16384
#define CONF_T 0.25f
#define NMS_T 0.45f
#define STRIDE 85

#define ROWS_PB 128
#define FLOATS_PB (ROWS_PB * STRIDE)   // 10880
#define F4_PB (FLOATS_PB / 4)          // 2720
#define REC_F 8                        // floats per record (padded to 32B)
#define MPAD 1002                      // LDS mask row pad
#define POOL64 19032                   // 152,256 B pool (phase-aliased)

__device__ __forceinline__ uint32_t f32_sortable(float f) {
    uint32_t u = __float_as_uint(f);
    return u ^ ((u >> 31) ? 0xFFFFFFFFu : 0x80000000u);
}

// 46-bit key: (sortable(masked_score) << 14) | (16383 - e).
// Descending key order == descending score, ascending index on ties (lax.top_k).

// Full-grid decode: coalesced float4 staging of 128 rows into LDS, per-row
// argmax over 80 classes + box decode. Emits sort key and (optionally)
// a 32B record (x1,y1,x2,y2,score,class) so no later stage re-reads pred.
__global__ __launch_bounds__(256) void decode_kernel(const float* __restrict__ pred,
                                                     uint64_t* __restrict__ keys,
                                                     float* __restrict__ recs) {
    __shared__ float s[FLOATS_PB];                 // 42.5 KiB
    const int blk = blockIdx.x;
    const int tid = threadIdx.x;
    const float4* g4 = (const float4*)pred + (size_t)blk * F4_PB;
    float4* s4 = (float4*)s;
    for (int i = tid; i < F4_PB; i += 256) s4[i] = g4[i];
    __syncthreads();
    if (tid < ROWS_PB) {
        const float* p = s + tid * STRIDE;         // stride 85 % 32 = 21, coprime -> conflict-free
        float cx = p[0], cy = p[1], w = p[2], h = p[3], obj = p[4];
        float best = p[5]; int bc = 0;
        #pragma unroll
        for (int c = 1; c < NUM_CLASSES; ++c) {
            float v = p[5 + c];
            if (v > best) { best = v; bc = c; }    // first-max wins, like jnp.argmax
        }
        float w2 = __fmul_rn(w, 0.5f), h2 = __fmul_rn(h, 0.5f);
        float score = __fmul_rn(obj, best);
        float masked = (score >= CONF_T) ? score : -1.0f;
        int r = blk * ROWS_PB + tid;               // global row = b*8400 + e
        int e = r % NPRED;
        keys[r] = ((uint64_t)f32_sortable(masked) << 14) | (uint32_t)(16383 - e);
        if (recs) {
            float4* rp = (float4*)(recs + (size_t)r * REC_F);
            rp[0] = make_float4(__fsub_rn(cx, w2), __fsub_rn(cy, h2),
                                __fadd_rn(cx, w2), __fadd_rn(cy, h2));
            rp[1] = make_float4(score, (float)bc, 0.0f, 0.0f);
        }
    }
}

// One block per batch: radix-select + bitonic sort (phase 1), record gather +
// in-LDS mask build (phase 2), VALU-chain greedy scan + output (phase 3).
// LDS pool aliased across phases: {keys+hist} -> {mask + raw box arrays}.
__global__ __launch_bounds__(1024) void fused_kernel(const uint64_t* __restrict__ keys,
                                                     const float* __restrict__ recs,
                                                     float* __restrict__ dets,
                                                     float* __restrict__ keep_out) {
    __shared__ uint64_t pool64[POOL64];            // 152,256 B, phase-aliased
    __shared__ uint64_t sortbuf[1024];             // 8 KiB, persists ph1->ph2
    __shared__ uint64_t removed_w[16];
    __shared__ uint32_t sh_rem, sh_cnt;
    __shared__ uint64_t sh_prefix;

    const int b = blockIdx.x;
    const int tid = threadIdx.x;
    const int lane = tid & 63, wid = tid >> 6;

    // ---------------- phase 1: exact radix select + bitonic sort ----------------
    uint64_t* k_lds = pool64;                      // [0 .. 67,200)
    uint32_t* hist = (uint32_t*)(pool64 + NPRED);  // [67,200 .. 83,584)
    uint32_t* wtot = hist + 4096;                  // 64 B

    for (int e = tid; e < NPRED; e += 1024) k_lds[e] = keys[(size_t)b * NPRED + e];
    if (tid == 0) { sh_rem = TOPK_N; sh_prefix = 0; sh_cnt = 0; }
    sortbuf[tid] = 0;                              // pads sink (real keys are much larger)
    __syncthreads();

    for (int shift = 36; shift >= 0; shift -= 12) {
        #pragma unroll
        for (int i = 0; i < 4; ++i) hist[tid * 4 + i] = 0;
        __syncthreads();
        const uint64_t himask = (shift == 36) ? 0ull : (~0ull << (shift + 12));
        const uint64_t pref = sh_prefix;
        const uint32_t rem = sh_rem;
        for (int e = tid; e < NPRED; e += 1024) {
            uint64_t k = k_lds[e];
            if ((k & himask) == (pref & himask))
                atomicAdd(&hist[(uint32_t)(k >> shift) & 4095u], 1u);
        }
        __syncthreads();
        uint32_t h0 = hist[tid * 4 + 0], h1 = hist[tid * 4 + 1];
        uint32_t h2 = hist[tid * 4 + 2], h3 = hist[tid * 4 + 3];
        uint32_t s4 = h0 + h1 + h2 + h3;
        uint32_t v = s4;
        #pragma unroll
        for (int off = 1; off < 64; off <<= 1) {   // wave inclusive suffix scan
            uint32_t u = __shfl_down(v, off);
            if (lane + off < 64) v += u;
        }
        if (lane == 0) wtot[wid] = v;
        __syncthreads();
        uint32_t carry = 0;
        for (int w = wid + 1; w < 16; ++w) carry += wtot[w];
        uint32_t S0 = v + carry;                   // suffix sum over bins >= 4*tid
        uint32_t carry_after = S0 - s4;
        if (carry_after < rem && S0 >= rem) {      // exactly one thread crosses
            uint32_t hh[4] = {h0, h1, h2, h3};
            uint32_t pre = 0, bestS = S0, besth = h0;
            int besti = 0;
            #pragma unroll
            for (int i = 0; i < 4; ++i) {
                uint32_t Si = S0 - pre;
                if (Si >= rem) { besti = i; bestS = Si; besth = hh[i]; }
                pre += hh[i];
            }
            sh_prefix = pref | ((uint64_t)(uint32_t)(tid * 4 + besti) << shift);
            sh_rem = rem - (bestS - besth);
        }
        __syncthreads();
    }

    const uint64_t T = sh_prefix;                  // exactly 1000 keys >= T
    for (int e = tid; e < NPRED; e += 1024) {
        uint64_t k = k_lds[e];
        if (k >= T) {
            uint32_t pos = atomicAdd(&sh_cnt, 1u);
            if (pos < 1024) sortbuf[pos] = k;
        }
    }
    __syncthreads();                               // last k_lds use

    for (unsigned k = 2; k <= 1024; k <<= 1) {     // bitonic sort descending
        for (unsigned j = k >> 1; j > 0; j >>= 1) {
            unsigned i = tid, ixj = i ^ j;
            if (ixj > i) {
                uint64_t a = sortbuf[i], c = sortbuf[ixj];
                bool desc = ((i & k) == 0);
                if (desc ? (a < c) : (a > c)) { sortbuf[i] = c; sortbuf[ixj] = a; }
            }
            __syncthreads();
        }
    }

    // ---------------- phase 2: gather records + in-LDS mask build ----------------
    uint64_t* lmask = pool64;                      // 16 x MPAD words [0 .. 128,256)
    float* rx1 = (float*)(pool64 + 16 * MPAD);     // [128,256 .. 152,256): 6 x 1000 f32
    float* ry1 = rx1 + TOPK_N;
    float* rx2 = ry1 + TOPK_N;
    float* ry2 = rx2 + TOPK_N;
    float* rsc = rx2 + 2 * TOPK_N;                 // = ry2 + TOPK_N
    float* rcl = rsc + TOPK_N;

    float4 r0 = make_float4(0, 0, 0, 0), r1 = make_float4(0, 0, 0, 0);
    bool invalid = false;
    if (tid < TOPK_N) {
        int e = 16383 - (int)((uint32_t)sortbuf[tid] & 16383u);
        const float4* rp = (const float4*)(recs + ((size_t)b * NPRED + e) * REC_F);
        r0 = rp[0]; r1 = rp[1];
        rx1[tid] = r0.x; ry1[tid] = r0.y; rx2[tid] = r0.z; ry2[tid] = r0.w;
        rsc[tid] = r1.x; rcl[tid] = r1.y;
        invalid = (r1.x < CONF_T);
    }
    {
        uint64_t bal = __ballot(invalid);
        if ((tid & 63) == 0) removed_w[tid >> 6] = bal;
    }
    __syncthreads();                               // raw arrays ready; k_lds/hist dead

    if (tid < TOPK_N) {
        const float ci = r1.y;
        const float off = __fmul_rn(ci, 10.0f);    // exact: class*10 <= 790
        const float ax1 = __fadd_rn(r0.x, off), ay1 = __fadd_rn(r0.y, off);
        const float ax2 = __fadd_rn(r0.z, off), ay2 = __fadd_rn(r0.w, off);
        const float areai = __fmul_rn(__fsub_rn(ax2, ax1), __fsub_rn(ay2, ay1));
        for (int w = 0; w < 16; ++w) {
            uint64_t bits = 0;
            const int base = w * 64;
            if (base + 63 > tid) {                 // chunk contains some j > row
                const int jend = min(TOPK_N - base, 64);
                for (int bb = 0; bb < jend; ++bb) {
                    int j = base + bb;
                    if (j <= tid) continue;
                    float jcl = rcl[j];            // broadcast-pattern LDS reads
                    if (jcl != ci) continue;       // diff class => disjoint after offset
                    float joff = __fmul_rn(jcl, 10.0f);   // == off (same class)
                    float jx1 = __fadd_rn(rx1[j], joff), jy1 = __fadd_rn(ry1[j], joff);
                    float jx2 = __fadd_rn(rx2[j], joff), jy2 = __fadd_rn(ry2[j], joff);
                    float areaj = __fmul_rn(__fsub_rn(jx2, jx1), __fsub_rn(jy2, jy1));
                    float ix1 = fmaxf(ax1, jx1), iy1 = fmaxf(ay1, jy1);
                    float ix2 = fminf(ax2, jx2), iy2 = fminf(ay2, jy2);
                    float dx = fmaxf(__fsub_rn(ix2, ix1), 0.0f);
                    float dy = fmaxf(__fsub_rn(iy2, iy1), 0.0f);
                    float inter = __fmul_rn(dx, dy);
                    float uni = __fsub_rn(__fadd_rn(areai, areaj), inter);
                    float iou = __fdiv_rn(inter, fmaxf(uni, 1e-9f));
                    if (iou > NMS_T) bits |= (1ull << bb);
                }
            }
            lmask[w * MPAD + tid] = bits;          // write all 16 words (zeros included)
        }
    }
    __syncthreads();

    // ---------------- phase 3: greedy scan (VALU-only dependent chain) ----------------
    if (tid < 64) {
        const int l = tid & 15;
        uint64_t rem = (tid < 16) ? removed_w[tid] : 0;
        for (int W = 0; W < 16; ++W) {
            uint64_t cur = __shfl(rem, W);         // word W incl. earlier suppressions
            const int base = W * 64;
            const int nb = min(64, TOPK_N - base);
            #pragma unroll 8
            for (int bb = 0; bb < nb; ++bb) {
                int i = base + bb;
                uint64_t mW = lmask[W * MPAD + i]; // broadcast read
                uint64_t ml = lmask[l * MPAD + i]; // own-row read
                uint64_t sel = ((cur >> bb) & 1ull) ? 0ull : ~0ull;
                cur |= (mW & sel);                 // mask[i] has no bits <= i
                rem |= (ml & sel);
            }
        }
        if (tid < 16) removed_w[tid] = rem;
    }
    __syncthreads();

    if (tid < TOPK_N) {
        bool kept = ((removed_w[tid >> 6] >> (tid & 63)) & 1ull) == 0;
        float* dr = dets + ((size_t)b * TOPK_N + tid) * 6;
        if (kept) {
            dr[0] = r0.x; dr[1] = r0.y; dr[2] = r0.z; dr[3] = r0.w;
            dr[4] = r1.x; dr[5] = r1.y;
        } else {
            dr[0] = 0.0f; dr[1] = 0.0f; dr[2] = 0.0f;
            dr[3] = 0.0f; dr[4] = 0.0f; dr[5] = 0.0f;
        }
        keep_out[b * TOPK_N + tid] = kept ? 1.0f : 0.0f;
    }
}

// ---------- fallback kernels (small ws) ----------

__global__ __launch_bounds__(1024) void select_kernel(const uint64_t* __restrict__ keys,
                                                      int* __restrict__ top_idx) {
    __shared__ uint64_t k_lds[NPRED];
    __shared__ uint64_t sortbuf[1024];
    __shared__ uint32_t hist[4096];
    __shared__ uint32_t wtot[16];
    __shared__ uint32_t sh_rem, sh_cnt;
    __shared__ uint64_t sh_prefix;
    const int b = blockIdx.x;
    const int tid = threadIdx.x;
    const int lane = tid & 63, wid = tid >> 6;

    for (int e = tid; e < NPRED; e += 1024) k_lds[e] = keys[(size_t)b * NPRED + e];
    if (tid == 0) { sh_rem = TOPK_N; sh_prefix = 0; sh_cnt = 0; }
    sortbuf[tid] = 0;
    __syncthreads();

    for (int shift = 36; shift >= 0; shift -= 12) {
        #pragma unroll
        for (int i = 0; i < 4; ++i) hist[tid * 4 + i] = 0;
        __syncthreads();
        const uint64_t himask = (shift == 36) ? 0ull : (~0ull << (shift + 12));
        const uint64_t pref = sh_prefix;
        const uint32_t rem = sh_rem;
        for (int e = tid; e < NPRED; e += 1024) {
            uint64_t k = k_lds[e];
            if ((k & himask) == (pref & himask))
                atomicAdd(&hist[(uint32_t)(k >> shift) & 4095u], 1u);
        }
        __syncthreads();
        uint32_t h0 = hist[tid * 4 + 0], h1 = hist[tid * 4 + 1];
        uint32_t h2 = hist[tid * 4 + 2], h3 = hist[tid * 4 + 3];
        uint32_t s4 = h0 + h1 + h2 + h3;
        uint32_t v = s4;
        #pragma unroll
        for (int off = 1; off < 64; off <<= 1) {
            uint32_t u = __shfl_down(v, off);
            if (lane + off < 64) v += u;
        }
        if (lane == 0) wtot[wid] = v;
        __syncthreads();
        uint32_t carry = 0;
        for (int w = wid + 1; w < 16; ++w) carry += wtot[w];
        uint32_t S0 = v + carry;
        uint32_t carry_after = S0 - s4;
        if (carry_after < rem && S0 >= rem) {
            uint32_t hh[4] = {h0, h1, h2, h3};
            uint32_t pre = 0, bestS = S0, besth = h0;
            int besti = 0;
            #pragma unroll
            for (int i = 0; i < 4; ++i) {
                uint32_t Si = S0 - pre;
                if (Si >= rem) { besti = i; bestS = Si; besth = hh[i]; }
                pre += hh[i];
            }
            sh_prefix = pref | ((uint64_t)(uint32_t)(tid * 4 + besti) << shift);
            sh_rem = rem - (bestS - besth);
        }
        __syncthreads();
    }

    const uint64_t T = sh_prefix;
    for (int e = tid; e < NPRED; e += 1024) {
        uint64_t k = k_lds[e];
        if (k >= T) {
            uint32_t pos = atomicAdd(&sh_cnt, 1u);
            if (pos < 1024) sortbuf[pos] = k;
        }
    }
    __syncthreads();

    for (unsigned k = 2; k <= 1024; k <<= 1) {
        for (unsigned j = k >> 1; j > 0; j >>= 1) {
            unsigned i = tid, ixj = i ^ j;
            if (ixj > i) {
                uint64_t a = sortbuf[i], c = sortbuf[ixj];
                bool desc = ((i & k) == 0);
                if (desc ? (a < c) : (a > c)) { sortbuf[i] = c; sortbuf[ixj] = a; }
            }
            __syncthreads();
        }
    }

    if (tid < TOPK_N)
        top_idx[b * TOPK_N + tid] = 16383 - (int)((uint32_t)sortbuf[tid] & 16383u);
}

__global__ __launch_bounds__(1024) void topk_kernel(const float* __restrict__ pred,
                                                    int* __restrict__ top_idx) {
    __shared__ uint64_t keys[SORTN];
    const int b = blockIdx.x;
    const int tid = threadIdx.x;
    const float* pb = pred + (size_t)b * NPRED * STRIDE;

    for (int e = tid; e < SORTN; e += 1024) {
        uint64_t key = 0;
        if (e < NPRED) {
            const float* p = pb + (size_t)e * STRIDE;
            float obj = p[4];
            float best = p[5];
            #pragma unroll 8
            for (int c = 1; c < NUM_CLASSES; ++c) best = fmaxf(best, p[5 + c]);
            float score = __fmul_rn(obj, best);
            float masked = (score >= CONF_T) ? score : -1.0f;
            key = ((uint64_t)f32_sortable(masked) << 32) | (uint32_t)(~(uint32_t)e);
        }
        keys[e] = key;
    }
    __syncthreads();
    for (unsigned k = 2; k <= SORTN; k <<= 1) {
        for (unsigned j = k >> 1; j > 0; j >>= 1) {
            for (unsigned i = tid; i < SORTN; i += 1024) {
                unsigned ixj = i ^ j;
                if (ixj > i) {
                    uint64_t a = keys[i], c = keys[ixj];
                    bool desc = ((i & k) == 0);
                    if (desc ? (a < c) : (a > c)) { keys[i] = c; keys[ixj] = a; }
                }
            }
            __syncthreads();
        }
    }
    for (int t = tid; t < TOPK_N; t += 1024) {
        top_idx[b * TOPK_N + t] = (int)(~(uint32_t)keys[t]);
    }
}

__global__ __launch_bounds__(1024) void nms_kernel(const float* __restrict__ pred,
                                                   const int* __restrict__ top_idx,
                                                   float* __restrict__ dets,
                                                   float* __restrict__ keep_out) {
    __shared__ uint64_t mask[TOPK_N * 16];
    __shared__ float lx1[TOPK_N], ly1[TOPK_N], lx2[TOPK_N], ly2[TOPK_N];
    __shared__ float lsc[TOPK_N], lcl[TOPK_N];
    __shared__ uint64_t removed_w[16];

    const int b = blockIdx.x;
    const int tid = threadIdx.x;
    const float* pb = pred + (size_t)b * NPRED * STRIDE;

    bool invalid = false;
    if (tid < TOPK_N) {
        int e = top_idx[b * TOPK_N + tid];
        const float* p = pb + (size_t)e * STRIDE;
        float cx = p[0], cy = p[1], w = p[2], h = p[3], obj = p[4];
        float best = p[5]; int bc = 0;
        for (int c = 1; c < NUM_CLASSES; ++c) {
            float v = p[5 + c];
            if (v > best) { best = v; bc = c; }
        }
        float w2 = __fmul_rn(w, 0.5f), h2 = __fmul_rn(h, 0.5f);
        float score = __fmul_rn(obj, best);
        lx1[tid] = __fsub_rn(cx, w2);
        ly1[tid] = __fsub_rn(cy, h2);
        lx2[tid] = __fadd_rn(cx, w2);
        ly2[tid] = __fadd_rn(cy, h2);
        lsc[tid] = score;
        lcl[tid] = (float)bc;
        invalid = (score < CONF_T);
    }
    {
        uint64_t bal = __ballot(invalid);
        if ((tid & 63) == 0) removed_w[tid >> 6] = bal;
    }
    __syncthreads();

    for (int p = tid; p < TOPK_N * 16; p += 1024) {
        int i = p >> 4, w = p & 15;
        float ci = lcl[i];
        float offi = __fmul_rn(ci, 10.0f);
        float ax1 = __fadd_rn(lx1[i], offi), ay1 = __fadd_rn(ly1[i], offi);
        float ax2 = __fadd_rn(lx2[i], offi), ay2 = __fadd_rn(ly2[i], offi);
        float areai = __fmul_rn(__fsub_rn(ax2, ax1), __fsub_rn(ay2, ay1));
        uint64_t bits = 0;
        int jend = min(TOPK_N - w * 64, 64);
        for (int bb = 0; bb < jend; ++bb) {
            int j = w * 64 + bb;
            if (j <= i) continue;
            if (lcl[j] != ci) continue;
            float bx1 = __fadd_rn(lx1[j], offi), by1 = __fadd_rn(ly1[j], offi);
            float bx2 = __fadd_rn(lx2[j], offi), by2 = __fadd_rn(ly2[j], offi);
            float areaj = __fmul_rn(__fsub_rn(bx2, bx1), __fsub_rn(by2, by1));
            float ix1 = fmaxf(ax1, bx1), iy1 = fmaxf(ay1, by1);
            float ix2 = fminf(ax2, bx2), iy2 = fminf(ay2, by2);
            float dx = fmaxf(__fsub_rn(ix2, ix1), 0.0f);
            float dy = fmaxf(__fsub_rn(iy2, iy1), 0.0f);
            float inter = __fmul_rn(dx, dy);
            float uni = __fsub_rn(__fadd_rn(areai, areaj), inter);
            float iou = __fdiv_rn(inter, fmaxf(uni, 1e-9f));
            if (iou > NMS_T) bits |= (1ull << bb);
        }
        mask[i * 16 + w] = bits;
    }
    __syncthreads();

    if (tid < 64) {
        int lane = tid;
        uint64_t rem = (lane < 16) ? removed_w[lane] : 0;
        for (int i = 0; i < TOPK_N; ++i) {
            uint64_t rw = __shfl(rem, i >> 6);
            bool alive = ((rw >> (i & 63)) & 1ull) == 0;
            uint64_t m = mask[i * 16 + (lane & 15)];
            if (alive && lane < 16) rem |= m;
        }
        if (lane < 16) removed_w[lane] = rem;
    }
    __syncthreads();

    for (int t = tid; t < TOPK_N; t += 1024) {
        bool kept = ((removed_w[t >> 6] >> (t & 63)) & 1ull) == 0;
        float* dr = dets + ((size_t)b * TOPK_N + t) * 6;
        if (kept) {
            dr[0] = lx1[t]; dr[1] = ly1[t]; dr[2] = lx2[t]; dr[3] = ly2[t];
            dr[4] = lsc[t]; dr[5] = lcl[t];
        } else {
            dr[0] = 0.0f; dr[1] = 0.0f; dr[2] = 0.0f;
            dr[3] = 0.0f; dr[4] = 0.0f; dr[5] = 0.0f;
        }
        keep_out[b * TOPK_N + t] = kept ? 1.0f : 0.0f;
    }
}

extern "C" void kernel_launch(void* const* d_in, const int* in_sizes, int n_in,
                              void* d_out, int out_size, void* d_ws, size_t ws_size,
                              hipStream_t stream) {
    const float* pred = (const float*)d_in[0];
    float* dets = (float*)d_out;                              // 32*1000*6
    float* keep = (float*)d_out + (size_t)NBATCH * TOPK_N * 6;

    const size_t total_rows = (size_t)NBATCH * NPRED;         // 268800
    const size_t keys_bytes = total_rows * sizeof(uint64_t);  // 2,150,400
    const size_t recs_bytes = total_rows * REC_F * sizeof(float); // 8,601,600
    const size_t idx_bytes  = (size_t)NBATCH * TOPK_N * sizeof(int); // 128,000

    if (ws_size >= keys_bytes + recs_bytes) {
        uint64_t* keys = (uint64_t*)d_ws;
        float* recs    = (float*)((char*)d_ws + keys_bytes);

        decode_kernel<<<(int)(total_rows / ROWS_PB), 256, 0, stream>>>(pred, keys, recs);
        fused_kernel<<<NBATCH, 1024, 0, stream>>>(keys, recs, dets, keep);
    } else if (ws_size >= keys_bytes + idx_bytes) {
        uint64_t* keys = (uint64_t*)d_ws;
        int* top_idx = (int*)((char*)d_ws + keys_bytes);
        decode_kernel<<<(int)(total_rows / ROWS_PB), 256, 0, stream>>>(pred, keys, nullptr);
        select_kernel<<<NBATCH, 1024, 0, stream>>>(keys, top_idx);
        nms_kernel<<<NBATCH, 1024, 0, stream>>>(pred, top_idx, dets, keep);
    } else {
        int* top_idx = (int*)d_ws;
        topk_kernel<<<NBATCH, 1024, 0, stream>>>(pred, top_idx);
        nms_kernel<<<NBATCH, 1024, 0, stream>>>(pred, top_idx, dets, keep);
    }
}

// Round 7
// 123.498 us; speedup vs baseline: 1.9506x; 1.9506x over previous
//
#include <hip/hip_runtime.h>
#include <cstdint>

#define NUM_CLASSES 80
#define NPRED 8400
#define NBATCH 32
#define TOPK_N 1000
#define SORTN 16384
#define CONF_T 0.25f
#define NMS_T 0.45f
#define STRIDE 85

#define ROWS_PB 128
#define FLOATS_PB (ROWS_PB * STRIDE)   // 10880
#define F4_PB (FLOATS_PB / 4)          // 2720
#define REC_F 8                        // floats per record (padded to 32B)
#define MPAD 1002                      // LDS mask row pad (breaks bank pattern)

__device__ __forceinline__ uint32_t f32_sortable(float f) {
    uint32_t u = __float_as_uint(f);
    return u ^ ((u >> 31) ? 0xFFFFFFFFu : 0x80000000u);
}

__device__ __forceinline__ uint64_t shfl_xor_u64(uint64_t x, int m) {
    uint32_t lo = (uint32_t)x, hi = (uint32_t)(x >> 32);
    lo = (uint32_t)__shfl_xor((int)lo, m);
    hi = (uint32_t)__shfl_xor((int)hi, m);
    return ((uint64_t)hi << 32) | lo;
}

// 46-bit key: (sortable(masked_score) << 14) | (16383 - e).
// Descending key order == descending score, ascending index on ties (lax.top_k).

// Full-grid decode: coalesced float4 staging of 128 rows into LDS, per-row
// argmax over 80 classes + box decode. Emits sort key and (optionally)
// a 32B record (x1,y1,x2,y2,score,class) so no later stage re-reads pred.
__global__ __launch_bounds__(256) void decode_kernel(const float* __restrict__ pred,
                                                     uint64_t* __restrict__ keys,
                                                     float* __restrict__ recs) {
    __shared__ float s[FLOATS_PB];                 // 42.5 KiB
    const int blk = blockIdx.x;
    const int tid = threadIdx.x;
    const float4* g4 = (const float4*)pred + (size_t)blk * F4_PB;
    float4* s4 = (float4*)s;
    for (int i = tid; i < F4_PB; i += 256) s4[i] = g4[i];
    __syncthreads();
    if (tid < ROWS_PB) {
        const float* p = s + tid * STRIDE;         // stride 85 % 32 = 21, coprime -> conflict-free
        float cx = p[0], cy = p[1], w = p[2], h = p[3], obj = p[4];
        float best = p[5]; int bc = 0;
        #pragma unroll
        for (int c = 1; c < NUM_CLASSES; ++c) {
            float v = p[5 + c];
            if (v > best) { best = v; bc = c; }    // first-max wins, like jnp.argmax
        }
        float w2 = __fmul_rn(w, 0.5f), h2 = __fmul_rn(h, 0.5f);
        float score = __fmul_rn(obj, best);
        float masked = (score >= CONF_T) ? score : -1.0f;
        int r = blk * ROWS_PB + tid;               // global row = b*8400 + e
        int e = r % NPRED;
        keys[r] = ((uint64_t)f32_sortable(masked) << 14) | (uint32_t)(16383 - e);
        if (recs) {
            float4* rp = (float4*)(recs + (size_t)r * REC_F);
            rp[0] = make_float4(__fsub_rn(cx, w2), __fsub_rn(cy, h2),
                                __fadd_rn(cx, w2), __fadd_rn(cy, h2));
            rp[1] = make_float4(score, (float)bc, 0.0f, 0.0f);
        }
    }
}

// One block per batch: exact radix-select (4 x 12-bit MSB passes, parallel
// suffix-scan bin selection). Invalid keys (masked==-1) are bulk-counted via
// ballot to kill the single-bin atomic storm; compaction is wave-aggregated;
// bitonic sort uses register shfl_xor for wave-internal stages.
__global__ __launch_bounds__(1024) void select_kernel(const uint64_t* __restrict__ keys,
                                                      int* __restrict__ top_idx) {
    __shared__ uint64_t k_lds[NPRED];              // 67.2 KiB
    __shared__ uint64_t sortbuf[1024];             // 8 KiB
    __shared__ uint32_t hist[4096];                // 16 KiB
    __shared__ uint32_t wtot[16];
    __shared__ uint32_t sh_rem, sh_cnt, sh_inv;
    __shared__ uint64_t sh_prefix;
    const int b = blockIdx.x;
    const int tid = threadIdx.x;
    const int lane = tid & 63, wid = tid >> 6;
    const uint64_t INV_HI = (uint64_t)f32_sortable(-1.0f);   // 0x407FFFFF

    if (tid == 0) { sh_rem = TOPK_N; sh_prefix = 0; sh_cnt = 0; sh_inv = 0; }
    sortbuf[tid] = 0;                              // pads sink (real keys are much larger)
    __syncthreads();

    // key load + per-wave ballot count of invalid (masked == -1) keys
    uint32_t invw = 0;
    for (int e0 = 0; e0 < NPRED; e0 += 1024) {
        int e = e0 + tid;
        uint64_t k = 0;
        if (e < NPRED) { k = keys[(size_t)b * NPRED + e]; k_lds[e] = k; }
        uint64_t bal = __ballot((e < NPRED) && ((k >> 14) == INV_HI));
        if (lane == 0) invw += (uint32_t)__popcll(bal);
    }
    if (lane == 0 && invw) atomicAdd(&sh_inv, invw);
    __syncthreads();

    for (int shift = 36; shift >= 0; shift -= 12) {
        #pragma unroll
        for (int i = 0; i < 4; ++i) hist[tid * 4 + i] = 0;
        __syncthreads();
        const uint64_t himask = (shift == 36) ? 0ull : (~0ull << (shift + 12));
        const uint64_t pref = sh_prefix;
        const uint32_t rem = sh_rem;
        if (shift == 36) {
            for (int e = tid; e < NPRED; e += 1024) {
                uint64_t k = k_lds[e];
                if ((k >> 14) != INV_HI)           // invalids bulk-added below
                    atomicAdd(&hist[(uint32_t)(k >> 36) & 4095u], 1u);
            }
            if (tid == 0) atomicAdd(&hist[(uint32_t)(INV_HI >> 22)], sh_inv);
        } else {
            for (int e = tid; e < NPRED; e += 1024) {
                uint64_t k = k_lds[e];
                if ((k & himask) == (pref & himask))
                    atomicAdd(&hist[(uint32_t)(k >> shift) & 4095u], 1u);
            }
        }
        __syncthreads();
        // each thread owns bins [4*tid .. 4*tid+3]; suffix sums descending
        uint32_t h0 = hist[tid * 4 + 0], h1 = hist[tid * 4 + 1];
        uint32_t h2 = hist[tid * 4 + 2], h3 = hist[tid * 4 + 3];
        uint32_t s4 = h0 + h1 + h2 + h3;
        uint32_t v = s4;
        #pragma unroll
        for (int off = 1; off < 64; off <<= 1) {   // wave inclusive suffix scan
            uint32_t u = __shfl_down(v, off);
            if (lane + off < 64) v += u;
        }
        if (lane == 0) wtot[wid] = v;
        __syncthreads();
        uint32_t carry = 0;
        for (int w = wid + 1; w < 16; ++w) carry += wtot[w];
        uint32_t S0 = v + carry;                   // suffix sum over bins >= 4*tid
        uint32_t carry_after = S0 - s4;            // sum over bins > 4*tid+3
        if (carry_after < rem && S0 >= rem) {      // exactly one thread crosses
            uint32_t hh[4] = {h0, h1, h2, h3};
            uint32_t pre = 0, bestS = S0, besth = h0;
            int besti = 0;
            #pragma unroll
            for (int i = 0; i < 4; ++i) {          // largest i with S(4t+i) >= rem
                uint32_t Si = S0 - pre;
                if (Si >= rem) { besti = i; bestS = Si; besth = hh[i]; }
                pre += hh[i];
            }
            sh_prefix = pref | ((uint64_t)(uint32_t)(tid * 4 + besti) << shift);
            sh_rem = rem - (bestS - besth);        // rem minus count strictly above chosen bin
        }
        __syncthreads();
    }

    // wave-aggregated compaction: exactly 1000 keys >= T (keys unique)
    const uint64_t T = sh_prefix;
    for (int e0 = 0; e0 < NPRED; e0 += 1024) {
        int e = e0 + tid;
        uint64_t k = (e < NPRED) ? k_lds[e] : 0;
        bool pred = (e < NPRED) && (k >= T);
        uint64_t bal = __ballot(pred);
        uint32_t base = 0;
        if (lane == 0 && bal) base = atomicAdd(&sh_cnt, (uint32_t)__popcll(bal));
        base = __shfl(base, 0);
        if (pred) {
            uint32_t pos = base + (uint32_t)__popcll(bal & ((1ull << lane) - 1ull));
            if (pos < 1024) sortbuf[pos] = k;
        }
    }
    __syncthreads();

    // bitonic sort descending: LDS only for j>=64, register shfl_xor inside wave
    uint64_t v64 = sortbuf[tid];
    for (unsigned k = 2; k <= 1024; k <<= 1) {
        for (unsigned j = k >> 1; j > 0; j >>= 1) {
            uint64_t o;
            if (j >= 64) {
                __syncthreads();
                sortbuf[tid] = v64;
                __syncthreads();
                o = sortbuf[tid ^ j];
            } else {
                o = shfl_xor_u64(v64, (int)j);
            }
            bool lower = (tid & j) == 0;
            bool desc = (tid & k) == 0;
            v64 = (lower == desc) ? (v64 > o ? v64 : o) : (v64 < o ? v64 : o);
        }
    }

    if (tid < TOPK_N)
        top_idx[b * TOPK_N + tid] = 16383 - (int)((uint32_t)v64 & 16383u);
}

// Mask build, conflict-free: block (w=col-block, b=batch). 64 column boxes staged
// in LDS (offset coords + area precomputed once per box); each thread owns 4 rows
// in registers and sweeps columns -> all LDS reads are same-address broadcasts.
__global__ __launch_bounds__(256) void maskbuild_kernel(const float* __restrict__ recs,
                                                        const int* __restrict__ top_idx,
                                                        uint64_t* __restrict__ mask) {
    __shared__ float cx1[64], cy1[64], cx2[64], cy2[64], car[64], ccl[64];
    const int w = blockIdx.x, b = blockIdx.y;
    const int tid = threadIdx.x;
    const int jbase = w * 64;
    const int jend = min(TOPK_N - jbase, 64);

    if (tid < jend) {
        int e = top_idx[b * TOPK_N + jbase + tid];
        const float4* rp = (const float4*)(recs + ((size_t)b * NPRED + e) * REC_F);
        float4 r0 = rp[0], r1 = rp[1];
        float off = __fmul_rn(r1.y, 10.0f);        // exact: class*10 <= 790
        float x1 = __fadd_rn(r0.x, off), y1 = __fadd_rn(r0.y, off);
        float x2 = __fadd_rn(r0.z, off), y2 = __fadd_rn(r0.w, off);
        cx1[tid] = x1; cy1[tid] = y1; cx2[tid] = x2; cy2[tid] = y2;
        car[tid] = __fmul_rn(__fsub_rn(x2, x1), __fsub_rn(y2, y1));
        ccl[tid] = r1.y;
    }
    __syncthreads();

    float rx1[4], ry1[4], rx2[4], ry2[4], rar[4], rcl[4];
    bool rv[4];
    #pragma unroll
    for (int q = 0; q < 4; ++q) {
        int r = tid + q * 256;
        rv[q] = (r < TOPK_N);
        if (rv[q]) {
            int e = top_idx[b * TOPK_N + r];
            const float4* rp = (const float4*)(recs + ((size_t)b * NPRED + e) * REC_F);
            float4 r0 = rp[0], r1 = rp[1];
            float off = __fmul_rn(r1.y, 10.0f);
            float x1 = __fadd_rn(r0.x, off), y1 = __fadd_rn(r0.y, off);
            float x2 = __fadd_rn(r0.z, off), y2 = __fadd_rn(r0.w, off);
            rx1[q] = x1; ry1[q] = y1; rx2[q] = x2; ry2[q] = y2;
            rar[q] = __fmul_rn(__fsub_rn(x2, x1), __fsub_rn(y2, y1));
            rcl[q] = r1.y;
        }
    }

    uint64_t bits[4] = {0, 0, 0, 0};
    for (int bb = 0; bb < jend; ++bb) {
        float jx1 = cx1[bb], jy1 = cy1[bb], jx2 = cx2[bb], jy2 = cy2[bb];
        float jar = car[bb], jcl = ccl[bb];
        int j = jbase + bb;
        #pragma unroll
        for (int q = 0; q < 4; ++q) {
            int r = tid + q * 256;
            if (!rv[q] || j <= r || jcl != rcl[q]) continue;  // diff class => disjoint after offset
            float ix1 = fmaxf(rx1[q], jx1), iy1 = fmaxf(ry1[q], jy1);
            float ix2 = fminf(rx2[q], jx2), iy2 = fminf(ry2[q], jy2);
            float dx = fmaxf(__fsub_rn(ix2, ix1), 0.0f);
            float dy = fmaxf(__fsub_rn(iy2, iy1), 0.0f);
            float inter = __fmul_rn(dx, dy);
            float uni = __fsub_rn(__fadd_rn(rar[q], jar), inter);
            float iou = __fdiv_rn(inter, fmaxf(uni, 1e-9f));
            if (iou > NMS_T) bits[q] |= (1ull << bb);
        }
    }
    #pragma unroll
    for (int q = 0; q < 4; ++q) {
        int r = tid + q * 256;
        if (rv[q]) mask[((size_t)b * 16 + w) * TOPK_N + r] = bits[q];
    }
}

// One block per batch: gather records, ballot invalid, mask -> LDS, one-wave
// greedy reduce with register-local current word (shfl only once per 64 cols),
// write dets + keep.
__global__ __launch_bounds__(1024) void reduce_kernel(const float* __restrict__ recs,
                                                      const int* __restrict__ top_idx,
                                                      const uint64_t* __restrict__ mask,
                                                      float* __restrict__ dets,
                                                      float* __restrict__ keep_out) {
    __shared__ uint64_t lmask[16 * MPAD];          // 125.3 KiB
    __shared__ uint64_t removed_w[16];
    const int b = blockIdx.x, tid = threadIdx.x;

    float4 r0 = make_float4(0, 0, 0, 0), r1 = make_float4(0, 0, 0, 0);
    bool invalid = false;
    if (tid < TOPK_N) {
        int e = top_idx[b * TOPK_N + tid];
        const float4* rp = (const float4*)(recs + ((size_t)b * NPRED + e) * REC_F);
        r0 = rp[0]; r1 = rp[1];
        invalid = (r1.x < CONF_T);
    }
    {
        uint64_t bal = __ballot(invalid);
        if ((tid & 63) == 0) removed_w[tid >> 6] = bal;
    }
    for (int p = tid; p < 16 * TOPK_N; p += 1024) {
        int w = p / TOPK_N, i = p - w * TOPK_N;
        lmask[w * MPAD + i] = mask[((size_t)b * 16 + w) * TOPK_N + i];
    }
    __syncthreads();

    // Greedy scan, one wave. Lanes 0..15 own removed words; ALL lanes maintain a
    // register copy `cur` of the current column-block's word via the broadcast
    // LDS read lmask[W][i]. Dependent chain is pure VALU; one shfl per 64 cols.
    if (tid < 64) {
        const int l = tid & 15;
        uint64_t rem = (tid < 16) ? removed_w[tid] : 0;
        for (int W = 0; W < 16; ++W) {
            uint64_t cur = __shfl(rem, W);         // word W incl. earlier suppressions
            const int base = W * 64;
            const int nb = min(64, TOPK_N - base);
            #pragma unroll 8
            for (int bb = 0; bb < nb; ++bb) {
                int i = base + bb;
                uint64_t mW = lmask[W * MPAD + i]; // broadcast read
                uint64_t ml = lmask[l * MPAD + i]; // own-row read
                uint64_t sel = ((cur >> bb) & 1ull) ? 0ull : ~0ull;
                cur |= (mW & sel);                 // mask[i] has no bits <= i
                rem |= (ml & sel);
            }
        }
        if (tid < 16) removed_w[tid] = rem;
    }
    __syncthreads();

    if (tid < TOPK_N) {
        bool kept = ((removed_w[tid >> 6] >> (tid & 63)) & 1ull) == 0;
        float* dr = dets + ((size_t)b * TOPK_N + tid) * 6;
        if (kept) {
            dr[0] = r0.x; dr[1] = r0.y; dr[2] = r0.z; dr[3] = r0.w;
            dr[4] = r1.x; dr[5] = r1.y;
        } else {
            dr[0] = 0.0f; dr[1] = 0.0f; dr[2] = 0.0f;
            dr[3] = 0.0f; dr[4] = 0.0f; dr[5] = 0.0f;
        }
        keep_out[b * TOPK_N + tid] = kept ? 1.0f : 0.0f;
    }
}

// ---------- fallback kernels (small ws) ----------

__global__ __launch_bounds__(1024) void topk_kernel(const float* __restrict__ pred,
                                                    int* __restrict__ top_idx) {
    __shared__ uint64_t keys[SORTN];
    const int b = blockIdx.x;
    const int tid = threadIdx.x;
    const float* pb = pred + (size_t)b * NPRED * STRIDE;

    for (int e = tid; e < SORTN; e += 1024) {
        uint64_t key = 0;
        if (e < NPRED) {
            const float* p = pb + (size_t)e * STRIDE;
            float obj = p[4];
            float best = p[5];
            #pragma unroll 8
            for (int c = 1; c < NUM_CLASSES; ++c) best = fmaxf(best, p[5 + c]);
            float score = __fmul_rn(obj, best);
            float masked = (score >= CONF_T) ? score : -1.0f;
            key = ((uint64_t)f32_sortable(masked) << 32) | (uint32_t)(~(uint32_t)e);
        }
        keys[e] = key;
    }
    __syncthreads();
    for (unsigned k = 2; k <= SORTN; k <<= 1) {
        for (unsigned j = k >> 1; j > 0; j >>= 1) {
            for (unsigned i = tid; i < SORTN; i += 1024) {
                unsigned ixj = i ^ j;
                if (ixj > i) {
                    uint64_t a = keys[i], c = keys[ixj];
                    bool desc = ((i & k) == 0);
                    if (desc ? (a < c) : (a > c)) { keys[i] = c; keys[ixj] = a; }
                }
            }
            __syncthreads();
        }
    }
    for (int t = tid; t < TOPK_N; t += 1024) {
        top_idx[b * TOPK_N + t] = (int)(~(uint32_t)keys[t]);
    }
}

__global__ __launch_bounds__(1024) void nms_kernel(const float* __restrict__ pred,
                                                   const int* __restrict__ top_idx,
                                                   float* __restrict__ dets,
                                                   float* __restrict__ keep_out) {
    __shared__ uint64_t mask[TOPK_N * 16];
    __shared__ float lx1[TOPK_N], ly1[TOPK_N], lx2[TOPK_N], ly2[TOPK_N];
    __shared__ float lsc[TOPK_N], lcl[TOPK_N];
    __shared__ uint64_t removed_w[16];

    const int b = blockIdx.x;
    const int tid = threadIdx.x;
    const float* pb = pred + (size_t)b * NPRED * STRIDE;

    bool invalid = false;
    if (tid < TOPK_N) {
        int e = top_idx[b * TOPK_N + tid];
        const float* p = pb + (size_t)e * STRIDE;
        float cx = p[0], cy = p[1], w = p[2], h = p[3], obj = p[4];
        float best = p[5]; int bc = 0;
        for (int c = 1; c < NUM_CLASSES; ++c) {
            float v = p[5 + c];
            if (v > best) { best = v; bc = c; }
        }
        float w2 = __fmul_rn(w, 0.5f), h2 = __fmul_rn(h, 0.5f);
        float score = __fmul_rn(obj, best);
        lx1[tid] = __fsub_rn(cx, w2);
        ly1[tid] = __fsub_rn(cy, h2);
        lx2[tid] = __fadd_rn(cx, w2);
        ly2[tid] = __fadd_rn(cy, h2);
        lsc[tid] = score;
        lcl[tid] = (float)bc;
        invalid = (score < CONF_T);
    }
    {
        uint64_t bal = __ballot(invalid);
        if ((tid & 63) == 0) removed_w[tid >> 6] = bal;
    }
    __syncthreads();

    for (int p = tid; p < TOPK_N * 16; p += 1024) {
        int i = p >> 4, w = p & 15;
        float ci = lcl[i];
        float offi = __fmul_rn(ci, 10.0f);
        float ax1 = __fadd_rn(lx1[i], offi), ay1 = __fadd_rn(ly1[i], offi);
        float ax2 = __fadd_rn(lx2[i], offi), ay2 = __fadd_rn(ly2[i], offi);
        float areai = __fmul_rn(__fsub_rn(ax2, ax1), __fsub_rn(ay2, ay1));
        uint64_t bits = 0;
        int jend = min(TOPK_N - w * 64, 64);
        for (int bb = 0; bb < jend; ++bb) {
            int j = w * 64 + bb;
            if (j <= i) continue;
            if (lcl[j] != ci) continue;
            float bx1 = __fadd_rn(lx1[j], offi), by1 = __fadd_rn(ly1[j], offi);
            float bx2 = __fadd_rn(lx2[j], offi), by2 = __fadd_rn(ly2[j], offi);
            float areaj = __fmul_rn(__fsub_rn(bx2, bx1), __fsub_rn(by2, by1));
            float ix1 = fmaxf(ax1, bx1), iy1 = fmaxf(ay1, by1);
            float ix2 = fminf(ax2, bx2), iy2 = fminf(ay2, by2);
            float dx = fmaxf(__fsub_rn(ix2, ix1), 0.0f);
            float dy = fmaxf(__fsub_rn(iy2, iy1), 0.0f);
            float inter = __fmul_rn(dx, dy);
            float uni = __fsub_rn(__fadd_rn(areai, areaj), inter);
            float iou = __fdiv_rn(inter, fmaxf(uni, 1e-9f));
            if (iou > NMS_T) bits |= (1ull << bb);
        }
        mask[i * 16 + w] = bits;
    }
    __syncthreads();

    if (tid < 64) {
        int lane = tid;
        uint64_t rem = (lane < 16) ? removed_w[lane] : 0;
        for (int i = 0; i < TOPK_N; ++i) {
            uint64_t rw = __shfl(rem, i >> 6);
            bool alive = ((rw >> (i & 63)) & 1ull) == 0;
            uint64_t m = mask[i * 16 + (lane & 15)];
            if (alive && lane < 16) rem |= m;
        }
        if (lane < 16) removed_w[lane] = rem;
    }
    __syncthreads();

    for (int t = tid; t < TOPK_N; t += 1024) {
        bool kept = ((removed_w[t >> 6] >> (t & 63)) & 1ull) == 0;
        float* dr = dets + ((size_t)b * TOPK_N + t) * 6;
        if (kept) {
            dr[0] = lx1[t]; dr[1] = ly1[t]; dr[2] = lx2[t]; dr[3] = ly2[t];
            dr[4] = lsc[t]; dr[5] = lcl[t];
        } else {
            dr[0] = 0.0f; dr[1] = 0.0f; dr[2] = 0.0f;
            dr[3] = 0.0f; dr[4] = 0.0f; dr[5] = 0.0f;
        }
        keep_out[b * TOPK_N + t] = kept ? 1.0f : 0.0f;
    }
}

extern "C" void kernel_launch(void* const* d_in, const int* in_sizes, int n_in,
                              void* d_out, int out_size, void* d_ws, size_t ws_size,
                              hipStream_t stream) {
    const float* pred = (const float*)d_in[0];
    float* dets = (float*)d_out;                              // 32*1000*6
    float* keep = (float*)d_out + (size_t)NBATCH * TOPK_N * 6;

    const size_t total_rows = (size_t)NBATCH * NPRED;         // 268800
    const size_t keys_bytes = total_rows * sizeof(uint64_t);  // 2,150,400
    const size_t recs_bytes = total_rows * REC_F * sizeof(float); // 8,601,600
    const size_t idx_bytes  = (size_t)NBATCH * TOPK_N * sizeof(int); // 128,000
    const size_t mask_bytes = (size_t)NBATCH * 16 * TOPK_N * sizeof(uint64_t); // 4,096,000

    if (ws_size >= keys_bytes + recs_bytes + idx_bytes + mask_bytes) {
        uint64_t* keys = (uint64_t*)d_ws;
        float* recs    = (float*)((char*)d_ws + keys_bytes);
        int* top_idx   = (int*)((char*)d_ws + keys_bytes + recs_bytes);
        uint64_t* mask = (uint64_t*)((char*)d_ws + keys_bytes + recs_bytes + idx_bytes);

        decode_kernel<<<(int)(total_rows / ROWS_PB), 256, 0, stream>>>(pred, keys, recs);
        select_kernel<<<NBATCH, 1024, 0, stream>>>(keys, top_idx);
        maskbuild_kernel<<<dim3(16, NBATCH), 256, 0, stream>>>(recs, top_idx, mask);
        reduce_kernel<<<NBATCH, 1024, 0, stream>>>(recs, top_idx, mask, dets, keep);
    } else if (ws_size >= keys_bytes + idx_bytes) {
        uint64_t* keys = (uint64_t*)d_ws;
        int* top_idx = (int*)((char*)d_ws + keys_bytes);
        decode_kernel<<<(int)(total_rows / ROWS_PB), 256, 0, stream>>>(pred, keys, nullptr);
        select_kernel<<<NBATCH, 1024, 0, stream>>>(keys, top_idx);
        nms_kernel<<<NBATCH, 1024, 0, stream>>>(pred, top_idx, dets, keep);
    } else {
        int* top_idx = (int*)d_ws;
        topk_kernel<<<NBATCH, 1024, 0, stream>>>(pred, top_idx);
        nms_kernel<<<NBATCH, 1024, 0, stream>>>(pred, top_idx, dets, keep);
    }
}

// Round 8
// 97.097 us; speedup vs baseline: 2.4810x; 1.2719x over previous
//
#include <hip/hip_runtime.h>
#include <cstdint>

#define NUM_CLASSES 80
#define NPRED 8400
#define NBATCH 32
#define TOPK_N 1000
#define SORTN 16384
#define CONF_T 0.25f
#define NMS_T 0.45f
#define STRIDE 85

#define ROWS_PB 128
#define FLOATS_PB (ROWS_PB * STRIDE)   // 10880
#define F4_PB (FLOATS_PB / 4)          // 2720
#define REC_F 8                        // floats per record (padded to 32B)
#define MPAD 1026                      // LDS mask row stride (1024 data + bank skew)

__device__ __forceinline__ uint32_t f32_sortable(float f) {
    uint32_t u = __float_as_uint(f);
    return u ^ ((u >> 31) ? 0xFFFFFFFFu : 0x80000000u);
}

__device__ __forceinline__ uint64_t shfl_xor_u64(uint64_t x, int m) {
    uint32_t lo = (uint32_t)x, hi = (uint32_t)(x >> 32);
    lo = (uint32_t)__shfl_xor((int)lo, m);
    hi = (uint32_t)__shfl_xor((int)hi, m);
    return ((uint64_t)hi << 32) | lo;
}

// 46-bit key: (sortable(masked_score) << 14) | (16383 - e).
// Descending key order == descending score, ascending index on ties (lax.top_k).

// Full-grid decode: coalesced float4 staging of 128 rows into LDS, per-row
// argmax over 80 classes + box decode. Emits sort key and (optionally)
// a 32B record (x1,y1,x2,y2,score,class) so no later stage re-reads pred.
__global__ __launch_bounds__(256) void decode_kernel(const float* __restrict__ pred,
                                                     uint64_t* __restrict__ keys,
                                                     float* __restrict__ recs) {
    __shared__ float s[FLOATS_PB];                 // 42.5 KiB
    const int blk = blockIdx.x;
    const int tid = threadIdx.x;
    const float4* g4 = (const float4*)pred + (size_t)blk * F4_PB;
    float4* s4 = (float4*)s;
    for (int i = tid; i < F4_PB; i += 256) s4[i] = g4[i];
    __syncthreads();
    if (tid < ROWS_PB) {
        const float* p = s + tid * STRIDE;         // stride 85 % 32 = 21, coprime -> conflict-free
        float cx = p[0], cy = p[1], w = p[2], h = p[3], obj = p[4];
        float best = p[5]; int bc = 0;
        #pragma unroll
        for (int c = 1; c < NUM_CLASSES; ++c) {
            float v = p[5 + c];
            if (v > best) { best = v; bc = c; }    // first-max wins, like jnp.argmax
        }
        float w2 = __fmul_rn(w, 0.5f), h2 = __fmul_rn(h, 0.5f);
        float score = __fmul_rn(obj, best);
        float masked = (score >= CONF_T) ? score : -1.0f;
        int r = blk * ROWS_PB + tid;               // global row = b*8400 + e
        int e = r % NPRED;
        keys[r] = ((uint64_t)f32_sortable(masked) << 14) | (uint32_t)(16383 - e);
        if (recs) {
            float4* rp = (float4*)(recs + (size_t)r * REC_F);
            rp[0] = make_float4(__fsub_rn(cx, w2), __fsub_rn(cy, h2),
                                __fadd_rn(cx, w2), __fadd_rn(cy, h2));
            rp[1] = make_float4(score, (float)bc, 0.0f, 0.0f);
        }
    }
}

// One block per batch: exact radix-select (4 x 12-bit MSB passes, parallel
// suffix-scan bin selection). Invalid keys (masked==-1) are bulk-counted via
// ballot to kill the single-bin atomic storm; compaction is wave-aggregated;
// bitonic sort uses register shfl_xor for wave-internal stages.
__global__ __launch_bounds__(1024) void select_kernel(const uint64_t* __restrict__ keys,
                                                      int* __restrict__ top_idx) {
    __shared__ uint64_t k_lds[NPRED];              // 67.2 KiB
    __shared__ uint64_t sortbuf[1024];             // 8 KiB
    __shared__ uint32_t hist[4096];                // 16 KiB
    __shared__ uint32_t wtot[16];
    __shared__ uint32_t sh_rem, sh_cnt, sh_inv;
    __shared__ uint64_t sh_prefix;
    const int b = blockIdx.x;
    const int tid = threadIdx.x;
    const int lane = tid & 63, wid = tid >> 6;
    const uint64_t INV_HI = (uint64_t)f32_sortable(-1.0f);   // 0x407FFFFF

    if (tid == 0) { sh_rem = TOPK_N; sh_prefix = 0; sh_cnt = 0; sh_inv = 0; }
    sortbuf[tid] = 0;                              // pads sink (real keys are much larger)
    __syncthreads();

    // key load + per-wave ballot count of invalid (masked == -1) keys
    uint32_t invw = 0;
    for (int e0 = 0; e0 < NPRED; e0 += 1024) {
        int e = e0 + tid;
        uint64_t k = 0;
        if (e < NPRED) { k = keys[(size_t)b * NPRED + e]; k_lds[e] = k; }
        uint64_t bal = __ballot((e < NPRED) && ((k >> 14) == INV_HI));
        if (lane == 0) invw += (uint32_t)__popcll(bal);
    }
    if (lane == 0 && invw) atomicAdd(&sh_inv, invw);
    __syncthreads();

    for (int shift = 36; shift >= 0; shift -= 12) {
        #pragma unroll
        for (int i = 0; i < 4; ++i) hist[tid * 4 + i] = 0;
        __syncthreads();
        const uint64_t himask = (shift == 36) ? 0ull : (~0ull << (shift + 12));
        const uint64_t pref = sh_prefix;
        const uint32_t rem = sh_rem;
        if (shift == 36) {
            for (int e = tid; e < NPRED; e += 1024) {
                uint64_t k = k_lds[e];
                if ((k >> 14) != INV_HI)           // invalids bulk-added below
                    atomicAdd(&hist[(uint32_t)(k >> 36) & 4095u], 1u);
            }
            if (tid == 0) atomicAdd(&hist[(uint32_t)(INV_HI >> 22)], sh_inv);
        } else {
            for (int e = tid; e < NPRED; e += 1024) {
                uint64_t k = k_lds[e];
                if ((k & himask) == (pref & himask))
                    atomicAdd(&hist[(uint32_t)(k >> shift) & 4095u], 1u);
            }
        }
        __syncthreads();
        // each thread owns bins [4*tid .. 4*tid+3]; suffix sums descending
        uint32_t h0 = hist[tid * 4 + 0], h1 = hist[tid * 4 + 1];
        uint32_t h2 = hist[tid * 4 + 2], h3 = hist[tid * 4 + 3];
        uint32_t s4 = h0 + h1 + h2 + h3;
        uint32_t v = s4;
        #pragma unroll
        for (int off = 1; off < 64; off <<= 1) {   // wave inclusive suffix scan
            uint32_t u = __shfl_down(v, off);
            if (lane + off < 64) v += u;
        }
        if (lane == 0) wtot[wid] = v;
        __syncthreads();
        uint32_t carry = 0;
        for (int w = wid + 1; w < 16; ++w) carry += wtot[w];
        uint32_t S0 = v + carry;                   // suffix sum over bins >= 4*tid
        uint32_t carry_after = S0 - s4;            // sum over bins > 4*tid+3
        if (carry_after < rem && S0 >= rem) {      // exactly one thread crosses
            uint32_t hh[4] = {h0, h1, h2, h3};
            uint32_t pre = 0, bestS = S0, besth = h0;
            int besti = 0;
            #pragma unroll
            for (int i = 0; i < 4; ++i) {          // largest i with S(4t+i) >= rem
                uint32_t Si = S0 - pre;
                if (Si >= rem) { besti = i; bestS = Si; besth = hh[i]; }
                pre += hh[i];
            }
            sh_prefix = pref | ((uint64_t)(uint32_t)(tid * 4 + besti) << shift);
            sh_rem = rem - (bestS - besth);        // rem minus count strictly above chosen bin
        }
        __syncthreads();
    }

    // wave-aggregated compaction: exactly 1000 keys >= T (keys unique)
    const uint64_t T = sh_prefix;
    for (int e0 = 0; e0 < NPRED; e0 += 1024) {
        int e = e0 + tid;
        uint64_t k = (e < NPRED) ? k_lds[e] : 0;
        bool pred = (e < NPRED) && (k >= T);
        uint64_t bal = __ballot(pred);
        uint32_t base = 0;
        if (lane == 0 && bal) base = atomicAdd(&sh_cnt, (uint32_t)__popcll(bal));
        base = __shfl(base, 0);
        if (pred) {
            uint32_t pos = base + (uint32_t)__popcll(bal & ((1ull << lane) - 1ull));
            if (pos < 1024) sortbuf[pos] = k;
        }
    }
    __syncthreads();

    // bitonic sort descending: LDS only for j>=64, register shfl_xor inside wave
    uint64_t v64 = sortbuf[tid];
    for (unsigned k = 2; k <= 1024; k <<= 1) {
        for (unsigned j = k >> 1; j > 0; j >>= 1) {
            uint64_t o;
            if (j >= 64) {
                __syncthreads();
                sortbuf[tid] = v64;
                __syncthreads();
                o = sortbuf[tid ^ j];
            } else {
                o = shfl_xor_u64(v64, (int)j);
            }
            bool lower = (tid & j) == 0;
            bool desc = (tid & k) == 0;
            v64 = (lower == desc) ? (v64 > o ? v64 : o) : (v64 < o ? v64 : o);
        }
    }

    if (tid < TOPK_N)
        top_idx[b * TOPK_N + tid] = 16383 - (int)((uint32_t)v64 & 16383u);
}

// Mask build: block (w=col-block, b=batch). 64 column boxes staged in LDS.
// Each thread owns 4 rows. Divergence fix: per (row, chunk) first build a
// class-match bitmap with a uniform non-divergent loop, then run the IoU body
// only on set bits (ctz iteration) -> wave pays ~max-matches (~4) bodies, not 64.
__global__ __launch_bounds__(256) void maskbuild_kernel(const float* __restrict__ recs,
                                                        const int* __restrict__ top_idx,
                                                        uint64_t* __restrict__ mask) {
    __shared__ float cx1[64], cy1[64], cx2[64], cy2[64], car[64], ccl[64];
    const int w = blockIdx.x, b = blockIdx.y;
    const int tid = threadIdx.x;
    const int jbase = w * 64;
    const int jend = min(TOPK_N - jbase, 64);

    if (tid < jend) {
        int e = top_idx[b * TOPK_N + jbase + tid];
        const float4* rp = (const float4*)(recs + ((size_t)b * NPRED + e) * REC_F);
        float4 r0 = rp[0], r1 = rp[1];
        float off = __fmul_rn(r1.y, 10.0f);        // exact: class*10 <= 790
        float x1 = __fadd_rn(r0.x, off), y1 = __fadd_rn(r0.y, off);
        float x2 = __fadd_rn(r0.z, off), y2 = __fadd_rn(r0.w, off);
        cx1[tid] = x1; cy1[tid] = y1; cx2[tid] = x2; cy2[tid] = y2;
        car[tid] = __fmul_rn(__fsub_rn(x2, x1), __fsub_rn(y2, y1));
        ccl[tid] = r1.y;
    }
    __syncthreads();

    float rx1[4], ry1[4], rx2[4], ry2[4], rar[4], rcl[4];
    bool rv[4];
    #pragma unroll
    for (int q = 0; q < 4; ++q) {
        int r = tid + q * 256;
        rv[q] = (r < TOPK_N);
        if (rv[q]) {
            int e = top_idx[b * TOPK_N + r];
            const float4* rp = (const float4*)(recs + ((size_t)b * NPRED + e) * REC_F);
            float4 r0 = rp[0], r1 = rp[1];
            float off = __fmul_rn(r1.y, 10.0f);
            float x1 = __fadd_rn(r0.x, off), y1 = __fadd_rn(r0.y, off);
            float x2 = __fadd_rn(r0.z, off), y2 = __fadd_rn(r0.w, off);
            rx1[q] = x1; ry1[q] = y1; rx2[q] = x2; ry2[q] = y2;
            rar[q] = __fmul_rn(__fsub_rn(x2, x1), __fsub_rn(y2, y1));
            rcl[q] = r1.y;
        }
    }

    uint64_t bits[4] = {0, 0, 0, 0};
    #pragma unroll
    for (int q = 0; q < 4; ++q) {
        if (!rv[q]) continue;
        const int r = tid + q * 256;
        // uniform, non-divergent bitmap build: same class AND j > r
        uint64_t bm = 0;
        for (int bb = 0; bb < jend; ++bb) {
            bool m = (ccl[bb] == rcl[q]) && ((jbase + bb) > r);
            bm |= m ? (1ull << bb) : 0ull;
        }
        // sparse IoU: ~0.8 set bits expected per (row, chunk)
        while (bm) {
            int bb = __builtin_ctzll(bm);
            bm &= bm - 1;
            float ix1 = fmaxf(rx1[q], cx1[bb]), iy1 = fmaxf(ry1[q], cy1[bb]);
            float ix2 = fminf(rx2[q], cx2[bb]), iy2 = fminf(ry2[q], cy2[bb]);
            float dx = fmaxf(__fsub_rn(ix2, ix1), 0.0f);
            float dy = fmaxf(__fsub_rn(iy2, iy1), 0.0f);
            float inter = __fmul_rn(dx, dy);
            float uni = __fsub_rn(__fadd_rn(rar[q], car[bb]), inter);
            float iou = __fdiv_rn(inter, fmaxf(uni, 1e-9f));
            if (iou > NMS_T) bits[q] |= (1ull << bb);
        }
    }
    #pragma unroll
    for (int q = 0; q < 4; ++q) {
        int r = tid + q * 256;
        if (rv[q]) mask[((size_t)b * 16 + w) * TOPK_N + r] = bits[q];
    }
}

// One block per batch: gather records, ballot invalid, mask -> LDS (rows
// zero-padded to 1024), one-wave greedy scan with 16-step register preloading
// (static-index arrays stay in VGPRs), write dets + keep.
__global__ __launch_bounds__(1024) void reduce_kernel(const float* __restrict__ recs,
                                                      const int* __restrict__ top_idx,
                                                      const uint64_t* __restrict__ mask,
                                                      float* __restrict__ dets,
                                                      float* __restrict__ keep_out) {
    __shared__ uint64_t lmask[16 * MPAD];          // 131.3 KiB (rows padded to 1024)
    __shared__ uint64_t removed_w[16];
    const int b = blockIdx.x, tid = threadIdx.x;

    // stage mask into LDS, zero-padding i in [1000, 1024)
    for (int p = tid; p < 16 * 1024; p += 1024) {
        int w = p >> 10, i = p & 1023;
        lmask[w * MPAD + i] = (i < TOPK_N) ? mask[((size_t)b * 16 + w) * TOPK_N + i] : 0ull;
    }

    float4 r0 = make_float4(0, 0, 0, 0), r1 = make_float4(0, 0, 0, 0);
    bool invalid = false;
    if (tid < TOPK_N) {
        int e = top_idx[b * TOPK_N + tid];
        const float4* rp = (const float4*)(recs + ((size_t)b * NPRED + e) * REC_F);
        r0 = rp[0]; r1 = rp[1];
        invalid = (r1.x < CONF_T);
    }
    {
        uint64_t bal = __ballot(invalid);
        if ((tid & 63) == 0) removed_w[tid >> 6] = bal;
    }
    __syncthreads();

    // Greedy scan, one wave. Lanes 0..15 own removed words; all lanes keep a
    // register copy `cur` of the current column-block's word (broadcast LDS
    // reads). 16-step register preload decouples LDS latency from the chain;
    // rows >= 1000 are alive with zero masks -> harmless.
    if (tid < 64) {
        const int l = tid & 15;
        uint64_t rem = (tid < 16) ? removed_w[tid] : 0;
        for (int W = 0; W < 16; ++W) {
            uint64_t cur = __shfl(rem, W);         // word W incl. earlier suppressions
            const int base = W * 64;
            #pragma unroll
            for (int sb = 0; sb < 64; sb += 16) {
                uint64_t mW[16], ml[16];
                #pragma unroll
                for (int q = 0; q < 16; ++q) {
                    int i = base + sb + q;
                    mW[q] = lmask[W * MPAD + i];   // broadcast read
                    ml[q] = lmask[l * MPAD + i];   // own-row read
                }
                #pragma unroll
                for (int q = 0; q < 16; ++q) {
                    int bb = sb + q;
                    uint64_t sel = ((cur >> bb) & 1ull) ? 0ull : ~0ull;
                    cur |= (mW[q] & sel);          // mask[i] has no bits <= i
                    rem |= (ml[q] & sel);
                }
            }
        }
        if (tid < 16) removed_w[tid] = rem;
    }
    __syncthreads();

    if (tid < TOPK_N) {
        bool kept = ((removed_w[tid >> 6] >> (tid & 63)) & 1ull) == 0;
        float* dr = dets + ((size_t)b * TOPK_N + tid) * 6;
        if (kept) {
            dr[0] = r0.x; dr[1] = r0.y; dr[2] = r0.z; dr[3] = r0.w;
            dr[4] = r1.x; dr[5] = r1.y;
        } else {
            dr[0] = 0.0f; dr[1] = 0.0f; dr[2] = 0.0f;
            dr[3] = 0.0f; dr[4] = 0.0f; dr[5] = 0.0f;
        }
        keep_out[b * TOPK_N + tid] = kept ? 1.0f : 0.0f;
    }
}

// ---------- fallback kernels (small ws) ----------

__global__ __launch_bounds__(1024) void topk_kernel(const float* __restrict__ pred,
                                                    int* __restrict__ top_idx) {
    __shared__ uint64_t keys[SORTN];
    const int b = blockIdx.x;
    const int tid = threadIdx.x;
    const float* pb = pred + (size_t)b * NPRED * STRIDE;

    for (int e = tid; e < SORTN; e += 1024) {
        uint64_t key = 0;
        if (e < NPRED) {
            const float* p = pb + (size_t)e * STRIDE;
            float obj = p[4];
            float best = p[5];
            #pragma unroll 8
            for (int c = 1; c < NUM_CLASSES; ++c) best = fmaxf(best, p[5 + c]);
            float score = __fmul_rn(obj, best);
            float masked = (score >= CONF_T) ? score : -1.0f;
            key = ((uint64_t)f32_sortable(masked) << 32) | (uint32_t)(~(uint32_t)e);
        }
        keys[e] = key;
    }
    __syncthreads();
    for (unsigned k = 2; k <= SORTN; k <<= 1) {
        for (unsigned j = k >> 1; j > 0; j >>= 1) {
            for (unsigned i = tid; i < SORTN; i += 1024) {
                unsigned ixj = i ^ j;
                if (ixj > i) {
                    uint64_t a = keys[i], c = keys[ixj];
                    bool desc = ((i & k) == 0);
                    if (desc ? (a < c) : (a > c)) { keys[i] = c; keys[ixj] = a; }
                }
            }
            __syncthreads();
        }
    }
    for (int t = tid; t < TOPK_N; t += 1024) {
        top_idx[b * TOPK_N + t] = (int)(~(uint32_t)keys[t]);
    }
}

__global__ __launch_bounds__(1024) void nms_kernel(const float* __restrict__ pred,
                                                   const int* __restrict__ top_idx,
                                                   float* __restrict__ dets,
                                                   float* __restrict__ keep_out) {
    __shared__ uint64_t mask[TOPK_N * 16];
    __shared__ float lx1[TOPK_N], ly1[TOPK_N], lx2[TOPK_N], ly2[TOPK_N];
    __shared__ float lsc[TOPK_N], lcl[TOPK_N];
    __shared__ uint64_t removed_w[16];

    const int b = blockIdx.x;
    const int tid = threadIdx.x;
    const float* pb = pred + (size_t)b * NPRED * STRIDE;

    bool invalid = false;
    if (tid < TOPK_N) {
        int e = top_idx[b * TOPK_N + tid];
        const float* p = pb + (size_t)e * STRIDE;
        float cx = p[0], cy = p[1], w = p[2], h = p[3], obj = p[4];
        float best = p[5]; int bc = 0;
        for (int c = 1; c < NUM_CLASSES; ++c) {
            float v = p[5 + c];
            if (v > best) { best = v; bc = c; }
        }
        float w2 = __fmul_rn(w, 0.5f), h2 = __fmul_rn(h, 0.5f);
        float score = __fmul_rn(obj, best);
        lx1[tid] = __fsub_rn(cx, w2);
        ly1[tid] = __fsub_rn(cy, h2);
        lx2[tid] = __fadd_rn(cx, w2);
        ly2[tid] = __fadd_rn(cy, h2);
        lsc[tid] = score;
        lcl[tid] = (float)bc;
        invalid = (score < CONF_T);
    }
    {
        uint64_t bal = __ballot(invalid);
        if ((tid & 63) == 0) removed_w[tid >> 6] = bal;
    }
    __syncthreads();

    for (int p = tid; p < TOPK_N * 16; p += 1024) {
        int i = p >> 4, w = p & 15;
        float ci = lcl[i];
        float offi = __fmul_rn(ci, 10.0f);
        float ax1 = __fadd_rn(lx1[i], offi), ay1 = __fadd_rn(ly1[i], offi);
        float ax2 = __fadd_rn(lx2[i], offi), ay2 = __fadd_rn(ly2[i], offi);
        float areai = __fmul_rn(__fsub_rn(ax2, ax1), __fsub_rn(ay2, ay1));
        uint64_t bits = 0;
        int jend = min(TOPK_N - w * 64, 64);
        for (int bb = 0; bb < jend; ++bb) {
            int j = w * 64 + bb;
            if (j <= i) continue;
            if (lcl[j] != ci) continue;
            float bx1 = __fadd_rn(lx1[j], offi), by1 = __fadd_rn(ly1[j], offi);
            float bx2 = __fadd_rn(lx2[j], offi), by2 = __fadd_rn(ly2[j], offi);
            float areaj = __fmul_rn(__fsub_rn(bx2, bx1), __fsub_rn(by2, by1));
            float ix1 = fmaxf(ax1, bx1), iy1 = fmaxf(ay1, by1);
            float ix2 = fminf(ax2, bx2), iy2 = fminf(ay2, by2);
            float dx = fmaxf(__fsub_rn(ix2, ix1), 0.0f);
            float dy = fmaxf(__fsub_rn(iy2, iy1), 0.0f);
            float inter = __fmul_rn(dx, dy);
            float uni = __fsub_rn(__fadd_rn(areai, areaj), inter);
            float iou = __fdiv_rn(inter, fmaxf(uni, 1e-9f));
            if (iou > NMS_T) bits |= (1ull << bb);
        }
        mask[i * 16 + w] = bits;
    }
    __syncthreads();

    if (tid < 64) {
        int lane = tid;
        uint64_t rem = (lane < 16) ? removed_w[lane] : 0;
        for (int i = 0; i < TOPK_N; ++i) {
            uint64_t rw = __shfl(rem, i >> 6);
            bool alive = ((rw >> (i & 63)) & 1ull) == 0;
            uint64_t m = mask[i * 16 + (lane & 15)];
            if (alive && lane < 16) rem |= m;
        }
        if (lane < 16) removed_w[lane] = rem;
    }
    __syncthreads();

    for (int t = tid; t < TOPK_N; t += 1024) {
        bool kept = ((removed_w[t >> 6] >> (t & 63)) & 1ull) == 0;
        float* dr = dets + ((size_t)b * TOPK_N + t) * 6;
        if (kept) {
            dr[0] = lx1[t]; dr[1] = ly1[t]; dr[2] = lx2[t]; dr[3] = ly2[t];
            dr[4] = lsc[t]; dr[5] = lcl[t];
        } else {
            dr[0] = 0.0f; dr[1] = 0.0f; dr[2] = 0.0f;
            dr[3] = 0.0f; dr[4] = 0.0f; dr[5] = 0.0f;
        }
        keep_out[b * TOPK_N + t] = kept ? 1.0f : 0.0f;
    }
}

extern "C" void kernel_launch(void* const* d_in, const int* in_sizes, int n_in,
                              void* d_out, int out_size, void* d_ws, size_t ws_size,
                              hipStream_t stream) {
    const float* pred = (const float*)d_in[0];
    float* dets = (float*)d_out;                              // 32*1000*6
    float* keep = (float*)d_out + (size_t)NBATCH * TOPK_N * 6;

    const size_t total_rows = (size_t)NBATCH * NPRED;         // 268800
    const size_t keys_bytes = total_rows * sizeof(uint64_t);  // 2,150,400
    const size_t recs_bytes = total_rows * REC_F * sizeof(float); // 8,601,600
    const size_t idx_bytes  = (size_t)NBATCH * TOPK_N * sizeof(int); // 128,000
    const size_t mask_bytes = (size_t)NBATCH * 16 * TOPK_N * sizeof(uint64_t); // 4,096,000

    if (ws_size >= keys_bytes + recs_bytes + idx_bytes + mask_bytes) {
        uint64_t* keys = (uint64_t*)d_ws;
        float* recs    = (float*)((char*)d_ws + keys_bytes);
        int* top_idx   = (int*)((char*)d_ws + keys_bytes + recs_bytes);
        uint64_t* mask = (uint64_t*)((char*)d_ws + keys_bytes + recs_bytes + idx_bytes);

        decode_kernel<<<(int)(total_rows / ROWS_PB), 256, 0, stream>>>(pred, keys, recs);
        select_kernel<<<NBATCH, 1024, 0, stream>>>(keys, top_idx);
        maskbuild_kernel<<<dim3(16, NBATCH), 256, 0, stream>>>(recs, top_idx, mask);
        reduce_kernel<<<NBATCH, 1024, 0, stream>>>(recs, top_idx, mask, dets, keep);
    } else if (ws_size >= keys_bytes + idx_bytes) {
        uint64_t* keys = (uint64_t*)d_ws;
        int* top_idx = (int*)((char*)d_ws + keys_bytes);
        decode_kernel<<<(int)(total_rows / ROWS_PB), 256, 0, stream>>>(pred, keys, nullptr);
        select_kernel<<<NBATCH, 1024, 0, stream>>>(keys, top_idx);
        nms_kernel<<<NBATCH, 1024, 0, stream>>>(pred, top_idx, dets, keep);
    } else {
        int* top_idx = (int*)d_ws;
        topk_kernel<<<NBATCH, 1024, 0, stream>>>(pred, top_idx);
        nms_kernel<<<NBATCH, 1024, 0, stream>>>(pred, top_idx, dets, keep);
    }
}

// Round 9
// 82.597 us; speedup vs baseline: 2.9165x; 1.1755x over previous
//
#include <hip/hip_runtime.h>
#include <cstdint>

#define NUM_CLASSES 80
#define NPRED 8400
#define NBATCH 32
#define TOPK_N 1000
#define SORTN 16384
#define CONF_T 0.25f
#define NMS_T 0.45f
#define STRIDE 85

#define ROWS_PB 128
#define FLOATS_PB (ROWS_PB * STRIDE)   // 10880
#define F4_PB (FLOATS_PB / 4)          // 2720
#define REC_F 8                        // floats per record (padded to 32B)
#define MPAD 1026                      // lmask row stride in words (bank skew)

// fused-kernel LDS pool layout (64-bit words):
//   phase 1: k_lds [0,8400) | hist (u32 x4096) [8400,10448) | sortbuf [10448,11472)
//   phase 2: lmask 16xMPAD [0,16416) | x1o/y1o/x2o/y2o (f32 x1000 each) [16416,18416)
//            | clsbm 16x80 [18416,19696)
#define POOLW 19696                    // 157,568 bytes

__device__ __forceinline__ uint32_t f32_sortable(float f) {
    uint32_t u = __float_as_uint(f);
    return u ^ ((u >> 31) ? 0xFFFFFFFFu : 0x80000000u);
}

__device__ __forceinline__ uint64_t shfl_xor_u64(uint64_t x, int m) {
    uint32_t lo = (uint32_t)x, hi = (uint32_t)(x >> 32);
    lo = (uint32_t)__shfl_xor((int)lo, m);
    hi = (uint32_t)__shfl_xor((int)hi, m);
    return ((uint64_t)hi << 32) | lo;
}

// 46-bit key: (sortable(masked_score) << 14) | (16383 - e).
// Descending key order == descending score, ascending index on ties (lax.top_k).

// Full-grid decode: coalesced float4 staging of 128 rows into LDS, per-row
// argmax over 80 classes + box decode. Emits sort key and (optionally)
// a 32B record (x1,y1,x2,y2,score,class) so no later stage re-reads pred.
__global__ __launch_bounds__(256) void decode_kernel(const float* __restrict__ pred,
                                                     uint64_t* __restrict__ keys,
                                                     float* __restrict__ recs) {
    __shared__ float s[FLOATS_PB];                 // 42.5 KiB
    const int blk = blockIdx.x;
    const int tid = threadIdx.x;
    const float4* g4 = (const float4*)pred + (size_t)blk * F4_PB;
    float4* s4 = (float4*)s;
    for (int i = tid; i < F4_PB; i += 256) s4[i] = g4[i];
    __syncthreads();
    if (tid < ROWS_PB) {
        const float* p = s + tid * STRIDE;         // stride 85 % 32 = 21, coprime -> conflict-free
        float cx = p[0], cy = p[1], w = p[2], h = p[3], obj = p[4];
        float best = p[5]; int bc = 0;
        #pragma unroll
        for (int c = 1; c < NUM_CLASSES; ++c) {
            float v = p[5 + c];
            if (v > best) { best = v; bc = c; }    // first-max wins, like jnp.argmax
        }
        float w2 = __fmul_rn(w, 0.5f), h2 = __fmul_rn(h, 0.5f);
        float score = __fmul_rn(obj, best);
        float masked = (score >= CONF_T) ? score : -1.0f;
        int r = blk * ROWS_PB + tid;               // global row = b*8400 + e
        int e = r % NPRED;
        keys[r] = ((uint64_t)f32_sortable(masked) << 14) | (uint32_t)(16383 - e);
        if (recs) {
            float4* rp = (float4*)(recs + (size_t)r * REC_F);
            rp[0] = make_float4(__fsub_rn(cx, w2), __fsub_rn(cy, h2),
                                __fadd_rn(cx, w2), __fadd_rn(cy, h2));
            rp[1] = make_float4(score, (float)bc, 0.0f, 0.0f);
        }
    }
}

// One block per batch, three phases in one kernel (no global roundtrips):
//  1) exact radix-select + hybrid bitonic sort -> sorted key in register v64
//  2) gather records once; build per-(chunk,class) bitmaps; sparse IoU mask
//     written straight into LDS (lane-consecutive -> conflict-free)
//  3) register-preload greedy scan; outputs from registers.
__global__ __launch_bounds__(1024) void fused_kernel(const uint64_t* __restrict__ keys,
                                                     const float* __restrict__ recs,
                                                     float* __restrict__ dets,
                                                     float* __restrict__ keep_out) {
    __shared__ uint64_t pool[POOLW];               // 157,568 B, phase-aliased
    __shared__ uint64_t removed_w[16];
    __shared__ uint32_t wtot[16];
    __shared__ uint32_t sh_rem, sh_cnt, sh_inv;
    __shared__ uint64_t sh_prefix;

    const int b = blockIdx.x;
    const int tid = threadIdx.x;
    const int lane = tid & 63, wid = tid >> 6;
    const uint64_t INV_HI = (uint64_t)f32_sortable(-1.0f);

    // ---------------- phase 1: radix select + bitonic (r8 select, LDS-pooled) ----------------
    uint64_t* k_lds = pool;                        // [0, 8400)
    uint32_t* hist = (uint32_t*)(pool + NPRED);    // 4096 u32
    uint64_t* sortbuf = pool + 10448;              // 1024 words

    if (tid == 0) { sh_rem = TOPK_N; sh_prefix = 0; sh_cnt = 0; sh_inv = 0; }
    sortbuf[tid] = 0;                              // pads sink (real keys are much larger)
    __syncthreads();

    uint32_t invw = 0;
    for (int e0 = 0; e0 < NPRED; e0 += 1024) {
        int e = e0 + tid;
        uint64_t k = 0;
        if (e < NPRED) { k = keys[(size_t)b * NPRED + e]; k_lds[e] = k; }
        uint64_t bal = __ballot((e < NPRED) && ((k >> 14) == INV_HI));
        if (lane == 0) invw += (uint32_t)__popcll(bal);
    }
    if (lane == 0 && invw) atomicAdd(&sh_inv, invw);
    __syncthreads();

    for (int shift = 36; shift >= 0; shift -= 12) {
        #pragma unroll
        for (int i = 0; i < 4; ++i) hist[tid * 4 + i] = 0;
        __syncthreads();
        const uint64_t himask = (shift == 36) ? 0ull : (~0ull << (shift + 12));
        const uint64_t pref = sh_prefix;
        const uint32_t rem = sh_rem;
        if (shift == 36) {
            for (int e = tid; e < NPRED; e += 1024) {
                uint64_t k = k_lds[e];
                if ((k >> 14) != INV_HI)           // invalids bulk-added below
                    atomicAdd(&hist[(uint32_t)(k >> 36) & 4095u], 1u);
            }
            if (tid == 0) atomicAdd(&hist[(uint32_t)(INV_HI >> 22)], sh_inv);
        } else {
            for (int e = tid; e < NPRED; e += 1024) {
                uint64_t k = k_lds[e];
                if ((k & himask) == (pref & himask))
                    atomicAdd(&hist[(uint32_t)(k >> shift) & 4095u], 1u);
            }
        }
        __syncthreads();
        uint32_t h0 = hist[tid * 4 + 0], h1 = hist[tid * 4 + 1];
        uint32_t h2 = hist[tid * 4 + 2], h3 = hist[tid * 4 + 3];
        uint32_t s4 = h0 + h1 + h2 + h3;
        uint32_t v = s4;
        #pragma unroll
        for (int off = 1; off < 64; off <<= 1) {   // wave inclusive suffix scan
            uint32_t u = __shfl_down(v, off);
            if (lane + off < 64) v += u;
        }
        if (lane == 0) wtot[wid] = v;
        __syncthreads();
        uint32_t carry = 0;
        for (int w = wid + 1; w < 16; ++w) carry += wtot[w];
        uint32_t S0 = v + carry;                   // suffix sum over bins >= 4*tid
        uint32_t carry_after = S0 - s4;
        if (carry_after < rem && S0 >= rem) {      // exactly one thread crosses
            uint32_t hh[4] = {h0, h1, h2, h3};
            uint32_t pre = 0, bestS = S0, besth = h0;
            int besti = 0;
            #pragma unroll
            for (int i = 0; i < 4; ++i) {
                uint32_t Si = S0 - pre;
                if (Si >= rem) { besti = i; bestS = Si; besth = hh[i]; }
                pre += hh[i];
            }
            sh_prefix = pref | ((uint64_t)(uint32_t)(tid * 4 + besti) << shift);
            sh_rem = rem - (bestS - besth);
        }
        __syncthreads();
    }

    const uint64_t T = sh_prefix;                  // exactly 1000 keys >= T (keys unique)
    for (int e0 = 0; e0 < NPRED; e0 += 1024) {
        int e = e0 + tid;
        uint64_t k = (e < NPRED) ? k_lds[e] : 0;
        bool pr = (e < NPRED) && (k >= T);
        uint64_t bal = __ballot(pr);
        uint32_t base = 0;
        if (lane == 0 && bal) base = atomicAdd(&sh_cnt, (uint32_t)__popcll(bal));
        base = __shfl(base, 0);
        if (pr) {
            uint32_t pos = base + (uint32_t)__popcll(bal & ((1ull << lane) - 1ull));
            if (pos < 1024) sortbuf[pos] = k;
        }
    }
    __syncthreads();

    uint64_t v64 = sortbuf[tid];
    for (unsigned k = 2; k <= 1024; k <<= 1) {
        for (unsigned j = k >> 1; j > 0; j >>= 1) {
            uint64_t o;
            if (j >= 64) {
                __syncthreads();
                sortbuf[tid] = v64;
                __syncthreads();
                o = sortbuf[tid ^ j];
            } else {
                o = shfl_xor_u64(v64, (int)j);
            }
            bool lower = (tid & j) == 0;
            bool desc = (tid & k) == 0;
            v64 = (lower == desc) ? (v64 > o ? v64 : o) : (v64 < o ? v64 : o);
        }
    }
    // thread tid now holds the tid-th key (desc) in v64; no LDS needed from phase 1.

    // ---------------- phase 2: gather + class bitmaps + in-LDS mask ----------------
    uint64_t* lmask = pool;                        // [0, 16416) words
    float* x1o = (float*)(pool + 16416);           // 4 x 1000 f32
    float* y1o = x1o + TOPK_N;
    float* x2o = y1o + TOPK_N;
    float* y2o = x2o + TOPK_N;
    uint64_t* clsbm = pool + 18416;                // 16 chunks x 80 classes

    float4 r0 = make_float4(0, 0, 0, 0), r1 = make_float4(0, 0, 0, 0);
    bool invalid = false;
    if (tid < TOPK_N) {
        int e = 16383 - (int)((uint32_t)v64 & 16383u);
        const float4* rp = (const float4*)(recs + ((size_t)b * NPRED + e) * REC_F);
        r0 = rp[0]; r1 = rp[1];
        invalid = (r1.x < CONF_T);
    }
    {
        uint64_t bal = __ballot(invalid);
        if ((tid & 63) == 0) removed_w[tid >> 6] = bal;
    }
    for (int i = tid; i < 16 * NUM_CLASSES; i += 1024) clsbm[i] = 0;  // no alias w/ phase-1 live data
    __syncthreads();                               // sort-era LDS reads all retired here

    float offv = 0.0f, ax1 = 0, ay1 = 0, ax2 = 0, ay2 = 0, areai = 0;
    int mycls = 0;
    if (tid < TOPK_N) {
        offv = __fmul_rn(r1.y, 10.0f);             // exact: class*10 <= 790
        ax1 = __fadd_rn(r0.x, offv); ay1 = __fadd_rn(r0.y, offv);
        ax2 = __fadd_rn(r0.z, offv); ay2 = __fadd_rn(r0.w, offv);
        areai = __fmul_rn(__fsub_rn(ax2, ax1), __fsub_rn(ay2, ay1));
        mycls = (int)r1.y;
        x1o[tid] = ax1; y1o[tid] = ay1; x2o[tid] = ax2; y2o[tid] = ay2;
        atomicOr(&clsbm[(tid >> 6) * NUM_CLASSES + mycls], 1ull << (tid & 63));
    }
    __syncthreads();

    const int myw = tid >> 6;
    if (tid < TOPK_N) {
        for (int w = 0; w < 16; ++w) {
            uint64_t bits = 0;
            if (w >= myw) {
                uint64_t bm = clsbm[w * NUM_CLASSES + mycls];
                if (w == myw) bm &= ~((2ull << (tid & 63)) - 1ull);   // keep j > tid only
                while (bm) {                       // ~0.4 set bits expected per chunk
                    int bb = __builtin_ctzll(bm);
                    bm &= bm - 1;
                    int j = w * 64 + bb;
                    float jx1 = x1o[j], jy1 = y1o[j], jx2 = x2o[j], jy2 = y2o[j];
                    float areaj = __fmul_rn(__fsub_rn(jx2, jx1), __fsub_rn(jy2, jy1));
                    float ix1 = fmaxf(ax1, jx1), iy1 = fmaxf(ay1, jy1);
                    float ix2 = fminf(ax2, jx2), iy2 = fminf(ay2, jy2);
                    float dx = fmaxf(__fsub_rn(ix2, ix1), 0.0f);
                    float dy = fmaxf(__fsub_rn(iy2, iy1), 0.0f);
                    float inter = __fmul_rn(dx, dy);
                    float uni = __fsub_rn(__fadd_rn(areai, areaj), inter);
                    float iou = __fdiv_rn(inter, fmaxf(uni, 1e-9f));
                    if (iou > NMS_T) bits |= (1ull << bb);
                }
            }
            lmask[w * MPAD + tid] = bits;          // lane-consecutive -> conflict-free
        }
    } else {
        #pragma unroll
        for (int w = 0; w < 16; ++w) lmask[w * MPAD + tid] = 0;  // phantom rows 1000..1023
    }
    __syncthreads();

    // ---------------- phase 3: greedy scan (register preload, VALU chain) ----------------
    if (tid < 64) {
        const int l = tid & 15;
        uint64_t rem = (tid < 16) ? removed_w[tid] : 0;
        for (int W = 0; W < 16; ++W) {
            uint64_t cur = __shfl(rem, W);         // word W incl. earlier suppressions
            const int base = W * 64;
            #pragma unroll
            for (int sb = 0; sb < 64; sb += 16) {
                uint64_t mW[16], ml[16];
                #pragma unroll
                for (int q = 0; q < 16; ++q) {
                    int i = base + sb + q;
                    mW[q] = lmask[W * MPAD + i];   // broadcast read
                    ml[q] = lmask[l * MPAD + i];   // own-row read (2-way = free)
                }
                #pragma unroll
                for (int q = 0; q < 16; ++q) {
                    int bb = sb + q;
                    uint64_t sel = ((cur >> bb) & 1ull) ? 0ull : ~0ull;
                    cur |= (mW[q] & sel);          // mask[i] has no bits <= i
                    rem |= (ml[q] & sel);
                }
            }
        }
        if (tid < 16) removed_w[tid] = rem;
    }
    __syncthreads();

    if (tid < TOPK_N) {
        bool kept = ((removed_w[tid >> 6] >> (tid & 63)) & 1ull) == 0;
        float* dr = dets + ((size_t)b * TOPK_N + tid) * 6;
        if (kept) {
            dr[0] = r0.x; dr[1] = r0.y; dr[2] = r0.z; dr[3] = r0.w;
            dr[4] = r1.x; dr[5] = r1.y;
        } else {
            dr[0] = 0.0f; dr[1] = 0.0f; dr[2] = 0.0f;
            dr[3] = 0.0f; dr[4] = 0.0f; dr[5] = 0.0f;
        }
        keep_out[b * TOPK_N + tid] = kept ? 1.0f : 0.0f;
    }
}

// ---------- fallback kernels (small ws) ----------

__global__ __launch_bounds__(1024) void select_kernel(const uint64_t* __restrict__ keys,
                                                      int* __restrict__ top_idx) {
    __shared__ uint64_t k_lds[NPRED];
    __shared__ uint64_t sortbuf[1024];
    __shared__ uint32_t hist[4096];
    __shared__ uint32_t wtot[16];
    __shared__ uint32_t sh_rem, sh_cnt, sh_inv;
    __shared__ uint64_t sh_prefix;
    const int b = blockIdx.x;
    const int tid = threadIdx.x;
    const int lane = tid & 63, wid = tid >> 6;
    const uint64_t INV_HI = (uint64_t)f32_sortable(-1.0f);

    if (tid == 0) { sh_rem = TOPK_N; sh_prefix = 0; sh_cnt = 0; sh_inv = 0; }
    sortbuf[tid] = 0;
    __syncthreads();

    uint32_t invw = 0;
    for (int e0 = 0; e0 < NPRED; e0 += 1024) {
        int e = e0 + tid;
        uint64_t k = 0;
        if (e < NPRED) { k = keys[(size_t)b * NPRED + e]; k_lds[e] = k; }
        uint64_t bal = __ballot((e < NPRED) && ((k >> 14) == INV_HI));
        if (lane == 0) invw += (uint32_t)__popcll(bal);
    }
    if (lane == 0 && invw) atomicAdd(&sh_inv, invw);
    __syncthreads();

    for (int shift = 36; shift >= 0; shift -= 12) {
        #pragma unroll
        for (int i = 0; i < 4; ++i) hist[tid * 4 + i] = 0;
        __syncthreads();
        const uint64_t himask = (shift == 36) ? 0ull : (~0ull << (shift + 12));
        const uint64_t pref = sh_prefix;
        const uint32_t rem = sh_rem;
        if (shift == 36) {
            for (int e = tid; e < NPRED; e += 1024) {
                uint64_t k = k_lds[e];
                if ((k >> 14) != INV_HI)
                    atomicAdd(&hist[(uint32_t)(k >> 36) & 4095u], 1u);
            }
            if (tid == 0) atomicAdd(&hist[(uint32_t)(INV_HI >> 22)], sh_inv);
        } else {
            for (int e = tid; e < NPRED; e += 1024) {
                uint64_t k = k_lds[e];
                if ((k & himask) == (pref & himask))
                    atomicAdd(&hist[(uint32_t)(k >> shift) & 4095u], 1u);
            }
        }
        __syncthreads();
        uint32_t h0 = hist[tid * 4 + 0], h1 = hist[tid * 4 + 1];
        uint32_t h2 = hist[tid * 4 + 2], h3 = hist[tid * 4 + 3];
        uint32_t s4 = h0 + h1 + h2 + h3;
        uint32_t v = s4;
        #pragma unroll
        for (int off = 1; off < 64; off <<= 1) {
            uint32_t u = __shfl_down(v, off);
            if (lane + off < 64) v += u;
        }
        if (lane == 0) wtot[wid] = v;
        __syncthreads();
        uint32_t carry = 0;
        for (int w = wid + 1; w < 16; ++w) carry += wtot[w];
        uint32_t S0 = v + carry;
        uint32_t carry_after = S0 - s4;
        if (carry_after < rem && S0 >= rem) {
            uint32_t hh[4] = {h0, h1, h2, h3};
            uint32_t pre = 0, bestS = S0, besth = h0;
            int besti = 0;
            #pragma unroll
            for (int i = 0; i < 4; ++i) {
                uint32_t Si = S0 - pre;
                if (Si >= rem) { besti = i; bestS = Si; besth = hh[i]; }
                pre += hh[i];
            }
            sh_prefix = pref | ((uint64_t)(uint32_t)(tid * 4 + besti) << shift);
            sh_rem = rem - (bestS - besth);
        }
        __syncthreads();
    }

    const uint64_t T = sh_prefix;
    for (int e0 = 0; e0 < NPRED; e0 += 1024) {
        int e = e0 + tid;
        uint64_t k = (e < NPRED) ? k_lds[e] : 0;
        bool pr = (e < NPRED) && (k >= T);
        uint64_t bal = __ballot(pr);
        uint32_t base = 0;
        if (lane == 0 && bal) base = atomicAdd(&sh_cnt, (uint32_t)__popcll(bal));
        base = __shfl(base, 0);
        if (pr) {
            uint32_t pos = base + (uint32_t)__popcll(bal & ((1ull << lane) - 1ull));
            if (pos < 1024) sortbuf[pos] = k;
        }
    }
    __syncthreads();

    uint64_t v64 = sortbuf[tid];
    for (unsigned k = 2; k <= 1024; k <<= 1) {
        for (unsigned j = k >> 1; j > 0; j >>= 1) {
            uint64_t o;
            if (j >= 64) {
                __syncthreads();
                sortbuf[tid] = v64;
                __syncthreads();
                o = sortbuf[tid ^ j];
            } else {
                o = shfl_xor_u64(v64, (int)j);
            }
            bool lower = (tid & j) == 0;
            bool desc = (tid & k) == 0;
            v64 = (lower == desc) ? (v64 > o ? v64 : o) : (v64 < o ? v64 : o);
        }
    }

    if (tid < TOPK_N)
        top_idx[b * TOPK_N + tid] = 16383 - (int)((uint32_t)v64 & 16383u);
}

__global__ __launch_bounds__(1024) void topk_kernel(const float* __restrict__ pred,
                                                    int* __restrict__ top_idx) {
    __shared__ uint64_t keys[SORTN];
    const int b = blockIdx.x;
    const int tid = threadIdx.x;
    const float* pb = pred + (size_t)b * NPRED * STRIDE;

    for (int e = tid; e < SORTN; e += 1024) {
        uint64_t key = 0;
        if (e < NPRED) {
            const float* p = pb + (size_t)e * STRIDE;
            float obj = p[4];
            float best = p[5];
            #pragma unroll 8
            for (int c = 1; c < NUM_CLASSES; ++c) best = fmaxf(best, p[5 + c]);
            float score = __fmul_rn(obj, best);
            float masked = (score >= CONF_T) ? score : -1.0f;
            key = ((uint64_t)f32_sortable(masked) << 32) | (uint32_t)(~(uint32_t)e);
        }
        keys[e] = key;
    }
    __syncthreads();
    for (unsigned k = 2; k <= SORTN; k <<= 1) {
        for (unsigned j = k >> 1; j > 0; j >>= 1) {
            for (unsigned i = tid; i < SORTN; i += 1024) {
                unsigned ixj = i ^ j;
                if (ixj > i) {
                    uint64_t a = keys[i], c = keys[ixj];
                    bool desc = ((i & k) == 0);
                    if (desc ? (a < c) : (a > c)) { keys[i] = c; keys[ixj] = a; }
                }
            }
            __syncthreads();
        }
    }
    for (int t = tid; t < TOPK_N; t += 1024) {
        top_idx[b * TOPK_N + t] = (int)(~(uint32_t)keys[t]);
    }
}

__global__ __launch_bounds__(1024) void nms_kernel(const float* __restrict__ pred,
                                                   const int* __restrict__ top_idx,
                                                   float* __restrict__ dets,
                                                   float* __restrict__ keep_out) {
    __shared__ uint64_t mask[TOPK_N * 16];
    __shared__ float lx1[TOPK_N], ly1[TOPK_N], lx2[TOPK_N], ly2[TOPK_N];
    __shared__ float lsc[TOPK_N], lcl[TOPK_N];
    __shared__ uint64_t removed_w[16];

    const int b = blockIdx.x;
    const int tid = threadIdx.x;
    const float* pb = pred + (size_t)b * NPRED * STRIDE;

    bool invalid = false;
    if (tid < TOPK_N) {
        int e = top_idx[b * TOPK_N + tid];
        const float* p = pb + (size_t)e * STRIDE;
        float cx = p[0], cy = p[1], w = p[2], h = p[3], obj = p[4];
        float best = p[5]; int bc = 0;
        for (int c = 1; c < NUM_CLASSES; ++c) {
            float v = p[5 + c];
            if (v > best) { best = v; bc = c; }
        }
        float w2 = __fmul_rn(w, 0.5f), h2 = __fmul_rn(h, 0.5f);
        float score = __fmul_rn(obj, best);
        lx1[tid] = __fsub_rn(cx, w2);
        ly1[tid] = __fsub_rn(cy, h2);
        lx2[tid] = __fadd_rn(cx, w2);
        ly2[tid] = __fadd_rn(cy, h2);
        lsc[tid] = score;
        lcl[tid] = (float)bc;
        invalid = (score < CONF_T);
    }
    {
        uint64_t bal = __ballot(invalid);
        if ((tid & 63) == 0) removed_w[tid >> 6] = bal;
    }
    __syncthreads();

    for (int p = tid; p < TOPK_N * 16; p += 1024) {
        int i = p >> 4, w = p & 15;
        float ci = lcl[i];
        float offi = __fmul_rn(ci, 10.0f);
        float ax1 = __fadd_rn(lx1[i], offi), ay1 = __fadd_rn(ly1[i], offi);
        float ax2 = __fadd_rn(lx2[i], offi), ay2 = __fadd_rn(ly2[i], offi);
        float areai = __fmul_rn(__fsub_rn(ax2, ax1), __fsub_rn(ay2, ay1));
        uint64_t bits = 0;
        int jend = min(TOPK_N - w * 64, 64);
        for (int bb = 0; bb < jend; ++bb) {
            int j = w * 64 + bb;
            if (j <= i) continue;
            if (lcl[j] != ci) continue;
            float bx1 = __fadd_rn(lx1[j], offi), by1 = __fadd_rn(ly1[j], offi);
            float bx2 = __fadd_rn(lx2[j], offi), by2 = __fadd_rn(ly2[j], offi);
            float areaj = __fmul_rn(__fsub_rn(bx2, bx1), __fsub_rn(by2, by1));
            float ix1 = fmaxf(ax1, bx1), iy1 = fmaxf(ay1, by1);
            float ix2 = fminf(ax2, bx2), iy2 = fminf(ay2, by2);
            float dx = fmaxf(__fsub_rn(ix2, ix1), 0.0f);
            float dy = fmaxf(__fsub_rn(iy2, iy1), 0.0f);
            float inter = __fmul_rn(dx, dy);
            float uni = __fsub_rn(__fadd_rn(areai, areaj), inter);
            float iou = __fdiv_rn(inter, fmaxf(uni, 1e-9f));
            if (iou > NMS_T) bits |= (1ull << bb);
        }
        mask[i * 16 + w] = bits;
    }
    __syncthreads();

    if (tid < 64) {
        int lane = tid;
        uint64_t rem = (lane < 16) ? removed_w[lane] : 0;
        for (int i = 0; i < TOPK_N; ++i) {
            uint64_t rw = __shfl(rem, i >> 6);
            bool alive = ((rw >> (i & 63)) & 1ull) == 0;
            uint64_t m = mask[i * 16 + (lane & 15)];
            if (alive && lane < 16) rem |= m;
        }
        if (lane < 16) removed_w[lane] = rem;
    }
    __syncthreads();

    for (int t = tid; t < TOPK_N; t += 1024) {
        bool kept = ((removed_w[t >> 6] >> (t & 63)) & 1ull) == 0;
        float* dr = dets + ((size_t)b * TOPK_N + t) * 6;
        if (kept) {
            dr[0] = lx1[t]; dr[1] = ly1[t]; dr[2] = lx2[t]; dr[3] = ly2[t];
            dr[4] = lsc[t]; dr[5] = lcl[t];
        } else {
            dr[0] = 0.0f; dr[1] = 0.0f; dr[2] = 0.0f;
            dr[3] = 0.0f; dr[4] = 0.0f; dr[5] = 0.0f;
        }
        keep_out[b * TOPK_N + t] = kept ? 1.0f : 0.0f;
    }
}

extern "C" void kernel_launch(void* const* d_in, const int* in_sizes, int n_in,
                              void* d_out, int out_size, void* d_ws, size_t ws_size,
                              hipStream_t stream) {
    const float* pred = (const float*)d_in[0];
    float* dets = (float*)d_out;                              // 32*1000*6
    float* keep = (float*)d_out + (size_t)NBATCH * TOPK_N * 6;

    const size_t total_rows = (size_t)NBATCH * NPRED;         // 268800
    const size_t keys_bytes = total_rows * sizeof(uint64_t);  // 2,150,400
    const size_t recs_bytes = total_rows * REC_F * sizeof(float); // 8,601,600
    const size_t idx_bytes  = (size_t)NBATCH * TOPK_N * sizeof(int); // 128,000

    if (ws_size >= keys_bytes + recs_bytes) {
        uint64_t* keys = (uint64_t*)d_ws;
        float* recs    = (float*)((char*)d_ws + keys_bytes);

        decode_kernel<<<(int)(total_rows / ROWS_PB), 256, 0, stream>>>(pred, keys, recs);
        fused_kernel<<<NBATCH, 1024, 0, stream>>>(keys, recs, dets, keep);
    } else if (ws_size >= keys_bytes + idx_bytes) {
        uint64_t* keys = (uint64_t*)d_ws;
        int* top_idx = (int*)((char*)d_ws + keys_bytes);
        decode_kernel<<<(int)(total_rows / ROWS_PB), 256, 0, stream>>>(pred, keys, nullptr);
        select_kernel<<<NBATCH, 1024, 0, stream>>>(keys, top_idx);
        nms_kernel<<<NBATCH, 1024, 0, stream>>>(pred, top_idx, dets, keep);
    } else {
        int* top_idx = (int*)d_ws;
        topk_kernel<<<NBATCH, 1024, 0, stream>>>(pred, top_idx);
        nms_kernel<<<NBATCH, 1024, 0, stream>>>(pred, top_idx, dets, keep);
    }
}